// Round 6
// baseline (547.962 us; speedup 1.0000x reference)
//
#include <hip/hip_runtime.h>
#include <math.h>

// Problem constants
#define DMODEL 256
#define HEADS  8
#define HDIM   32
#define BS     4
#define NQ     100
#define NPTS   25
#define LQ     2500      // NQ*NPTS
#define M10K   10000     // BS*LQ
#define LEN_IN 21760
#define MVAL   87040     // BS*LEN_IN

typedef float f32x4 __attribute__((ext_vector_type(4)));
typedef short s16x8 __attribute__((ext_vector_type(8)));
typedef unsigned short u16;

// fp32 -> bf16 round-to-nearest-even
static __device__ __forceinline__ short f2bf(float f) {
    unsigned u = __builtin_bit_cast(unsigned, f);
    u = (u + 0x7fffu + ((u >> 16) & 1u)) >> 16;
    return (short)u;
}
static __device__ __forceinline__ unsigned pack2(float lo, float hi) {
    return (unsigned)(u16)f2bf(lo) | ((unsigned)(u16)f2bf(hi) << 16);
}
static __device__ __forceinline__ float bf_lo(unsigned u) {
    return __builtin_bit_cast(float, u << 16);
}
static __device__ __forceinline__ float bf_hi(unsigned u) {
    return __builtin_bit_cast(float, u & 0xffff0000u);
}

#define LDSK 40   // padded bf16 row stride

// ---------------------------------------------------------------------------
// One-shot weight conversion: 10 fp32 weight matrices -> concatenated bf16.
// ---------------------------------------------------------------------------
__global__ __launch_bounds__(256) void convert_weights_kernel(
    const float* __restrict__ s0, const float* __restrict__ s1,
    const float* __restrict__ s2, const float* __restrict__ s3,
    const float* __restrict__ s4, const float* __restrict__ s5,
    const float* __restrict__ s6, const float* __restrict__ s7,
    const float* __restrict__ s8, const float* __restrict__ s9,
    u16* __restrict__ dst)
{
    int t8 = (blockIdx.x * 256 + threadIdx.x) * 8;
    if (t8 >= 1277952) return;
    const float* s; int base;
    if      (t8 <  196608) { s = s0; base = 0;       }
    else if (t8 <  262144) { s = s1; base = 196608;  }
    else if (t8 <  458752) { s = s2; base = 262144;  }
    else if (t8 <  524288) { s = s3; base = 458752;  }
    else if (t8 <  589824) { s = s4; base = 524288;  }
    else if (t8 <  622592) { s = s5; base = 589824;  }
    else if (t8 <  688128) { s = s6; base = 622592;  }
    else if (t8 <  753664) { s = s7; base = 688128;  }
    else if (t8 < 1015808) { s = s8; base = 753664;  }
    else                   { s = s9; base = 1015808; }
    const float* p = s + (t8 - base);
    float4 a = *(const float4*)p;
    float4 b = *(const float4*)(p + 4);
    s16x8 v;
    v[0]=f2bf(a.x); v[1]=f2bf(a.y); v[2]=f2bf(a.z); v[3]=f2bf(a.w);
    v[4]=f2bf(b.x); v[5]=f2bf(b.y); v[6]=f2bf(b.z); v[7]=f2bf(b.w);
    *(s16x8*)(dst + t8) = v;
}

// ---------------------------------------------------------------------------
// xb = bf16(a + b) (b optional); ab = bf16(a) (optional). 8 elems/thread.
// ---------------------------------------------------------------------------
__global__ __launch_bounds__(256) void add_convert_kernel(
    const float* __restrict__ a, const float* __restrict__ b,
    u16* __restrict__ xb, u16* __restrict__ ab, int n8)
{
    int i = blockIdx.x * 256 + threadIdx.x;
    if (i >= n8) return;
    size_t o = (size_t)i * 8;
    float4 a0 = *(const float4*)(a + o);
    float4 a1 = *(const float4*)(a + o + 4);
    if (ab) {
        s16x8 v;
        v[0]=f2bf(a0.x); v[1]=f2bf(a0.y); v[2]=f2bf(a0.z); v[3]=f2bf(a0.w);
        v[4]=f2bf(a1.x); v[5]=f2bf(a1.y); v[6]=f2bf(a1.z); v[7]=f2bf(a1.w);
        *(s16x8*)(ab + o) = v;
    }
    if (b) {
        float4 b0 = *(const float4*)(b + o);
        float4 b1 = *(const float4*)(b + o + 4);
        a0.x += b0.x; a0.y += b0.y; a0.z += b0.z; a0.w += b0.w;
        a1.x += b1.x; a1.y += b1.y; a1.z += b1.z; a1.w += b1.w;
    }
    s16x8 v;
    v[0]=f2bf(a0.x); v[1]=f2bf(a0.y); v[2]=f2bf(a0.z); v[3]=f2bf(a0.w);
    v[4]=f2bf(a1.x); v[5]=f2bf(a1.y); v[6]=f2bf(a1.z); v[7]=f2bf(a1.w);
    *(s16x8*)(xb + o) = v;
}

// ---------------------------------------------------------------------------
// 64x64-tile bf16 MFMA GEMM (kept for N=128 aw GEMM only).
// ---------------------------------------------------------------------------
__global__ __launch_bounds__(256) void gemm_mfma_kernel(
    const u16* __restrict__ A, int lda,
    const u16* __restrict__ W, int K,
    const float* __restrict__ bias,
    float* __restrict__ C, int ldc, int M)
{
    __shared__ short As[64 * LDSK];
    __shared__ short Ws[64 * LDSK];

    const int tid = threadIdx.x;
    const int m0 = blockIdx.y * 64, n0 = blockIdx.x * 64;
    const int srow = tid >> 2;
    const int skseg = (tid & 3) * 8;
    const int wave = tid >> 6;
    const int wm = wave & 1, wn = wave >> 1;
    const int lane = tid & 63;
    const int lrow = lane & 15;
    const int kq = lane >> 4;

    f32x4 acc[2][2];
#pragma unroll
    for (int i = 0; i < 2; ++i)
#pragma unroll
        for (int j = 0; j < 2; ++j) acc[i][j] = (f32x4)(0.f);

    for (int k0 = 0; k0 < K; k0 += 32) {
        int gm = m0 + srow;
        s16x8 av = (s16x8)0;
        if (gm < M) av = *(const s16x8*)(A + (size_t)gm * lda + k0 + skseg);
        s16x8 wv = *(const s16x8*)(W + (size_t)(n0 + srow) * K + k0 + skseg);
        *(s16x8*)&As[srow * LDSK + skseg] = av;
        *(s16x8*)&Ws[srow * LDSK + skseg] = wv;
        __syncthreads();

        s16x8 af[2], bfv[2];
#pragma unroll
        for (int i = 0; i < 2; ++i)
            af[i] = *(const s16x8*)&As[(wm * 32 + i * 16 + lrow) * LDSK + kq * 8];
#pragma unroll
        for (int j = 0; j < 2; ++j)
            bfv[j] = *(const s16x8*)&Ws[(wn * 32 + j * 16 + lrow) * LDSK + kq * 8];
#pragma unroll
        for (int i = 0; i < 2; ++i)
#pragma unroll
            for (int j = 0; j < 2; ++j)
                acc[i][j] = __builtin_amdgcn_mfma_f32_16x16x32_bf16(af[i], bfv[j], acc[i][j], 0, 0, 0);
        __syncthreads();
    }

#pragma unroll
    for (int i = 0; i < 2; ++i)
#pragma unroll
        for (int j = 0; j < 2; ++j) {
            int col = n0 + wn * 32 + j * 16 + lrow;
            float bv = bias[col];
#pragma unroll
            for (int reg = 0; reg < 4; ++reg) {
                int gm = m0 + wm * 32 + i * 16 + kq * 4 + reg;
                if (gm < M) C[(size_t)gm * ldc + col] = acc[i][j][reg] + bv;
            }
        }
}

// ---------------------------------------------------------------------------
// 128x128-tile bf16 MFMA GEMM: C[M,N] = A[M,K] @ W[N,K]^T + bias[N].
// A bf16, W bf16 (pre-converted). 256 threads, BK=32, 4 waves in 2x2 of
// 64x64 quadrants; each wave 4x4 of 16x16x32 MFMA per k-step (16 MFMA vs
// 8 ds_read_b128 -- 2x the MFMA:LDS ratio of the 64^2 tile).
// ---------------------------------------------------------------------------
__global__ __launch_bounds__(256) void gemm_mfma128_kernel(
    const u16* __restrict__ A, int lda,
    const u16* __restrict__ W, int K,
    const float* __restrict__ bias,
    void* __restrict__ Cv, int ldc,
    int M, int relu, int out_bf16)
{
    __shared__ short As[128 * LDSK];   // 10 KB
    __shared__ short Ws[128 * LDSK];   // 10 KB

    const int tid = threadIdx.x;
    const int m0 = blockIdx.y * 128, n0 = blockIdx.x * 128;

    const int srow = tid >> 1;            // 0..127
    const int sk = (tid & 1) * 16;        // 0 or 16

    const int wave = tid >> 6;
    const int wm = wave & 1, wn = wave >> 1;
    const int lane = tid & 63;
    const int lrow = lane & 15;
    const int kq = lane >> 4;

    f32x4 acc[4][4];
#pragma unroll
    for (int i = 0; i < 4; ++i)
#pragma unroll
        for (int j = 0; j < 4; ++j) acc[i][j] = (f32x4)(0.f);

    for (int k0 = 0; k0 < K; k0 += 32) {
        int gm = m0 + srow;
        s16x8 a0 = (s16x8)0, a1 = (s16x8)0;
        if (gm < M) {
            const u16* ap = A + (size_t)gm * lda + k0 + sk;
            a0 = *(const s16x8*)ap;
            a1 = *(const s16x8*)(ap + 8);
        }
        const u16* wp = W + (size_t)(n0 + srow) * K + k0 + sk;
        s16x8 w0 = *(const s16x8*)wp;
        s16x8 w1 = *(const s16x8*)(wp + 8);
        *(s16x8*)&As[srow * LDSK + sk]     = a0;
        *(s16x8*)&As[srow * LDSK + sk + 8] = a1;
        *(s16x8*)&Ws[srow * LDSK + sk]     = w0;
        *(s16x8*)&Ws[srow * LDSK + sk + 8] = w1;
        __syncthreads();

        s16x8 af[4], bfv[4];
#pragma unroll
        for (int i = 0; i < 4; ++i)
            af[i] = *(const s16x8*)&As[(wm * 64 + i * 16 + lrow) * LDSK + kq * 8];
#pragma unroll
        for (int j = 0; j < 4; ++j)
            bfv[j] = *(const s16x8*)&Ws[(wn * 64 + j * 16 + lrow) * LDSK + kq * 8];
#pragma unroll
        for (int i = 0; i < 4; ++i)
#pragma unroll
            for (int j = 0; j < 4; ++j)
                acc[i][j] = __builtin_amdgcn_mfma_f32_16x16x32_bf16(af[i], bfv[j], acc[i][j], 0, 0, 0);
        __syncthreads();
    }

#pragma unroll
    for (int i = 0; i < 4; ++i)
#pragma unroll
        for (int j = 0; j < 4; ++j) {
            int col = n0 + wn * 64 + j * 16 + lrow;
            float bv = bias[col];
#pragma unroll
            for (int reg = 0; reg < 4; ++reg) {
                int gm = m0 + wm * 64 + i * 16 + kq * 4 + reg;
                if (gm < M) {
                    float v = acc[i][j][reg] + bv;
                    if (relu) v = fmaxf(v, 0.f);
                    if (out_bf16)
                        ((u16*)Cv)[(size_t)gm * ldc + col] = (u16)f2bf(v);
                    else
                        ((float*)Cv)[(size_t)gm * ldc + col] = v;
                }
            }
        }
}

// ---------------------------------------------------------------------------
// Value GEMM: full-N tile (64 rows x 256 cols), K=N=256. A fp32 (converted
// during staging -- A is read from HBM exactly ONCE), W bf16, C bf16.
// Wave w computes cols w*64..w*64+63 over all 64 rows.
// ---------------------------------------------------------------------------
__global__ __launch_bounds__(256) void gemm_value_kernel(
    const float* __restrict__ A,
    const u16* __restrict__ W,
    const float* __restrict__ bias,
    u16* __restrict__ C, int M)
{
    __shared__ short As[64 * LDSK];    // 5 KB
    __shared__ short Ws[256 * LDSK];   // 20.5 KB

    const int tid = threadIdx.x;
    const int m0 = blockIdx.x * 64;

    const int arow = tid >> 2;
    const int ak = (tid & 3) * 8;

    const int wave = tid >> 6;
    const int lane = tid & 63;
    const int lrow = lane & 15;
    const int kq = lane >> 4;

    f32x4 acc[4][4];
#pragma unroll
    for (int i = 0; i < 4; ++i)
#pragma unroll
        for (int j = 0; j < 4; ++j) acc[i][j] = (f32x4)(0.f);

    for (int k0 = 0; k0 < 256; k0 += 32) {
        // A: 64x32 fp32 -> bf16
        int gm = m0 + arow;
        s16x8 av = (s16x8)0;
        if (gm < M) {
            const float* ap = A + (size_t)gm * 256 + k0 + ak;
            float4 a0 = *(const float4*)ap;
            float4 a1 = *(const float4*)(ap + 4);
            av[0]=f2bf(a0.x); av[1]=f2bf(a0.y); av[2]=f2bf(a0.z); av[3]=f2bf(a0.w);
            av[4]=f2bf(a1.x); av[5]=f2bf(a1.y); av[6]=f2bf(a1.z); av[7]=f2bf(a1.w);
        }
        *(s16x8*)&As[arow * LDSK + ak] = av;
        // W: 256x32 bf16 (L2-resident; 128 KB total per block over the k-loop)
#pragma unroll
        for (int it = 0; it < 4; ++it) {
            int n = (tid >> 2) + it * 64;
            s16x8 wv = *(const s16x8*)(W + (size_t)n * 256 + k0 + ak);
            *(s16x8*)&Ws[n * LDSK + ak] = wv;
        }
        __syncthreads();

        s16x8 af[4], bfv[4];
#pragma unroll
        for (int i = 0; i < 4; ++i)
            af[i] = *(const s16x8*)&As[(i * 16 + lrow) * LDSK + kq * 8];
#pragma unroll
        for (int j = 0; j < 4; ++j)
            bfv[j] = *(const s16x8*)&Ws[(wave * 64 + j * 16 + lrow) * LDSK + kq * 8];
#pragma unroll
        for (int i = 0; i < 4; ++i)
#pragma unroll
            for (int j = 0; j < 4; ++j)
                acc[i][j] = __builtin_amdgcn_mfma_f32_16x16x32_bf16(af[i], bfv[j], acc[i][j], 0, 0, 0);
        __syncthreads();
    }

#pragma unroll
    for (int i = 0; i < 4; ++i)
#pragma unroll
        for (int j = 0; j < 4; ++j) {
            int col = wave * 64 + j * 16 + lrow;
            float bv = bias[col];
#pragma unroll
            for (int reg = 0; reg < 4; ++reg) {
                int gm = m0 + i * 16 + kq * 4 + reg;
                if (gm < M)
                    C[(size_t)gm * 256 + col] = (u16)f2bf(acc[i][j][reg] + bv);
            }
        }
}

// ---------------------------------------------------------------------------
// Inter attention (S=100). Block = 512 threads per (b,h).
// ---------------------------------------------------------------------------
__global__ __launch_bounds__(512) void inter_attn_kernel(
    const float* __restrict__ qkv, u16* __restrict__ out, float scale)
{
    __shared__ float4 Kv[100][16];
    __shared__ float4 Ml4[100];
    __shared__ float4 Ll4[100];
    __shared__ float  O[100][33];

    const int b = blockIdx.x, h = blockIdx.y;
    const float* base = qkv + (size_t)b * 100 * 768;
    const int tid = threadIdx.x;
    const int r = tid & 127, kc = tid >> 7;

    for (int idx = tid; idx < 1600; idx += 512) {
        int row = idx >> 4, seg = idx & 15;
        const float* src = (seg < 8)
            ? base + row * 768 + 256 + h * 32 + seg * 4
            : base + row * 768 + 512 + h * 32 + (seg - 8) * 4;
        Kv[row][seg] = *(const float4*)src;
    }
    for (int idx = tid; idx < 100 * 33; idx += 512)
        ((float*)O)[idx] = 0.f;

    float q[32];
    if (r < 100) {
        const float* qp = base + r * 768 + h * 32;
#pragma unroll
        for (int c4 = 0; c4 < 8; ++c4) {
            float4 f = *(const float4*)(qp + c4 * 4);
            q[c4*4+0] = f.x; q[c4*4+1] = f.y; q[c4*4+2] = f.z; q[c4*4+3] = f.w;
        }
    }
    __syncthreads();

    float m = -1e30f, l = 0.f, acc[32];
#pragma unroll
    for (int c = 0; c < 32; ++c) acc[c] = 0.f;

    if (r < 100) {
        const int j0 = kc * 25;
#pragma unroll 2
        for (int s = 0; s < 25; ++s) {
            const float4* kr = &Kv[j0 + s][0];
            float dot = 0.f;
#pragma unroll
            for (int c4 = 0; c4 < 8; ++c4) {
                float4 kf = kr[c4];
                dot = fmaf(q[c4*4+0], kf.x, dot);
                dot = fmaf(q[c4*4+1], kf.y, dot);
                dot = fmaf(q[c4*4+2], kf.z, dot);
                dot = fmaf(q[c4*4+3], kf.w, dot);
            }
            dot *= scale;
            float mn = fmaxf(m, dot);
            float alpha = __expf(m - mn);
            float p = __expf(dot - mn);
            l = l * alpha + p;
            const float4* vr = &Kv[j0 + s][8];
#pragma unroll
            for (int c4 = 0; c4 < 8; ++c4) {
                float4 vf = vr[c4];
                acc[c4*4+0] = acc[c4*4+0] * alpha + p * vf.x;
                acc[c4*4+1] = acc[c4*4+1] * alpha + p * vf.y;
                acc[c4*4+2] = acc[c4*4+2] * alpha + p * vf.z;
                acc[c4*4+3] = acc[c4*4+3] * alpha + p * vf.w;
            }
            m = mn;
        }
        ((float*)&Ml4[r])[kc] = m;
        ((float*)&Ll4[r])[kc] = l;
    }
    __syncthreads();

    float alphaK = 0.f, Ltot = 1.f;
    if (r < 100) {
        float4 mv = Ml4[r];
        float4 lv = Ll4[r];
        float M = fmaxf(fmaxf(mv.x, mv.y), fmaxf(mv.z, mv.w));
        Ltot = __expf(mv.x - M) * lv.x + __expf(mv.y - M) * lv.y
             + __expf(mv.z - M) * lv.z + __expf(mv.w - M) * lv.w;
        alphaK = __expf(m - M);
    }
    for (int cc = 0; cc < 4; ++cc) {
        if (kc == cc && r < 100) {
#pragma unroll
            for (int c = 0; c < 32; ++c) O[r][c] += alphaK * acc[c];
        }
        __syncthreads();
    }
    if (kc == 0 && r < 100) {
        float inv = 1.f / Ltot;
        unsigned* op = (unsigned*)(out + ((size_t)b * 100 + r) * 256 + h * 32);
#pragma unroll
        for (int c = 0; c < 16; ++c)
            op[c] = pack2(O[r][2*c] * inv, O[r][2*c+1] * inv);
    }
}

// ---------------------------------------------------------------------------
// Intra attention (S=25). Block = 256 threads per batch-block.
// ---------------------------------------------------------------------------
__global__ __launch_bounds__(256) void intra_attn_kernel(
    const float* __restrict__ qkv, u16* __restrict__ out, float scale)
{
    __shared__ float4 KV[25][128];

    const int b = blockIdx.x;
    const int h = threadIdx.x >> 5, r = threadIdx.x & 31;
    const float* base = qkv + (size_t)b * 25 * 768;

    for (int idx = threadIdx.x; idx < 3200; idx += 256) {
        int row = idx >> 7, c = idx & 127;
        KV[row][c] = *(const float4*)(base + row * 768 + 256 + c * 4);
    }

    float q[32];
    if (r < 25) {
        const float* qp = base + r * 768 + h * 32;
#pragma unroll
        for (int c4 = 0; c4 < 8; ++c4) {
            float4 f = *(const float4*)(qp + c4 * 4);
            q[c4*4+0] = f.x; q[c4*4+1] = f.y; q[c4*4+2] = f.z; q[c4*4+3] = f.w;
        }
    }
    __syncthreads();

    if (r < 25) {
        float m = -1e30f, l = 0.f, acc[32];
#pragma unroll
        for (int c = 0; c < 32; ++c) acc[c] = 0.f;
#pragma unroll 2
        for (int j = 0; j < 25; ++j) {
            const float4* kr = &KV[j][h * 8];
            float dot = 0.f;
#pragma unroll
            for (int c4 = 0; c4 < 8; ++c4) {
                float4 kf = kr[c4];
                dot = fmaf(q[c4*4+0], kf.x, dot);
                dot = fmaf(q[c4*4+1], kf.y, dot);
                dot = fmaf(q[c4*4+2], kf.z, dot);
                dot = fmaf(q[c4*4+3], kf.w, dot);
            }
            dot *= scale;
            float mn = fmaxf(m, dot);
            float alpha = __expf(m - mn);
            float p = __expf(dot - mn);
            l = l * alpha + p;
            const float4* vr = &KV[j][64 + h * 8];
#pragma unroll
            for (int c4 = 0; c4 < 8; ++c4) {
                float4 vf = vr[c4];
                acc[c4*4+0] = acc[c4*4+0] * alpha + p * vf.x;
                acc[c4*4+1] = acc[c4*4+1] * alpha + p * vf.y;
                acc[c4*4+2] = acc[c4*4+2] * alpha + p * vf.z;
                acc[c4*4+3] = acc[c4*4+3] * alpha + p * vf.w;
            }
            m = mn;
        }
        float inv = 1.f / l;
        unsigned* op = (unsigned*)(out + ((size_t)b * 25 + r) * 256 + h * 32);
#pragma unroll
        for (int c = 0; c < 16; ++c)
            op[c] = pack2(acc[2*c] * inv, acc[2*c+1] * inv);
    }
}

// ---------------------------------------------------------------------------
// out[row] = LN(a[row] + b[row]) * g + beta; optional bf16 mirror out_bf.
// ---------------------------------------------------------------------------
__global__ __launch_bounds__(64) void add_ln_kernel(
    const float* __restrict__ a, const float* __restrict__ b,
    const float* __restrict__ g, const float* __restrict__ beta,
    float* __restrict__ out, u16* __restrict__ out_bf, int transpose_mode)
{
    const int r = blockIdx.x;
    const int lane = threadIdx.x;
    const float* ar = a + (size_t)r * 256;
    const float* br = b + (size_t)r * 256;
    float x[4];
    float s = 0.f;
#pragma unroll
    for (int i = 0; i < 4; ++i) {
        x[i] = ar[lane + 64 * i] + br[lane + 64 * i];
        s += x[i];
    }
#pragma unroll
    for (int off = 32; off >= 1; off >>= 1) s += __shfl_xor(s, off);
    float mean = s * (1.f / 256.f);
    float vs = 0.f;
#pragma unroll
    for (int i = 0; i < 4; ++i) { float d = x[i] - mean; vs += d * d; }
#pragma unroll
    for (int off = 32; off >= 1; off >>= 1) vs += __shfl_xor(vs, off);
    float rstd = rsqrtf(vs * (1.f / 256.f) + 1e-5f);

    size_t ro = r;
    if (transpose_mode) {
        int q = r % 100; int bp = r / 100; int p = bp % 25; int bb = bp / 25;
        ro = ((size_t)bb * 100 + q) * 25 + p;
    }
    float* orow = out + ro * 256;
    u16* brow = out_bf ? out_bf + ro * 256 : (u16*)0;
#pragma unroll
    for (int i = 0; i < 4; ++i) {
        int c = lane + 64 * i;
        float v = (x[i] - mean) * rstd * g[c] + beta[c];
        orow[c] = v;
        if (brow) brow[c] = (u16)f2bf(v);
    }
}

// ---------------------------------------------------------------------------
// ti[(b*25+p)*100+q][:] = tgt1[(b*100+q)*25+p][:]  (fp32 + bf16 mirror)
// ---------------------------------------------------------------------------
__global__ __launch_bounds__(64) void tgt_to_ti_kernel(
    const float* __restrict__ tgt1, float* __restrict__ ti, u16* __restrict__ tib)
{
    const int r = blockIdx.x;              // ti row
    int q = r % 100; int bp = r / 100; int p = bp % 25; int b = bp / 25;
    const float4* srcp = (const float4*)(tgt1 + (((size_t)b * 100 + q) * 25 + p) * 256);
    float4 v = srcp[threadIdx.x];
    ((float4*)(ti + (size_t)r * 256))[threadIdx.x] = v;
    uint2 pk = make_uint2(pack2(v.x, v.y), pack2(v.z, v.w));
    ((uint2*)(tib + (size_t)r * 256))[threadIdx.x] = pk;
}

// ---------------------------------------------------------------------------
// MSDeform sampling, bf16 value, 8 channels/thread, bf16 output.
// ---------------------------------------------------------------------------
__global__ __launch_bounds__(256, 4) void msdeform_sample_kernel(
    const u16* __restrict__ value,
    const float* __restrict__ off,
    const float* __restrict__ awl,
    const float* __restrict__ refp,
    u16* __restrict__ sampled)
{
    const int unit = blockIdx.x * 8 + (threadIdx.x >> 5);
    const int t = threadIdx.x & 31;
    const int h = t >> 2, c8 = t & 3;
    const int b = unit / LQ, lq = unit - b * LQ;
    const int q = lq / NPTS;

    const float* awp = awl + (size_t)unit * 128 + h * 16;
    float w[16];
    float mx = -1e30f;
#pragma unroll
    for (int k = 0; k < 16; ++k) { w[k] = awp[k]; mx = fmaxf(mx, w[k]); }
    float sum = 0.f;
#pragma unroll
    for (int k = 0; k < 16; ++k) { w[k] = __expf(w[k] - mx); sum += w[k]; }
    const float inv = 1.f / sum;

    const float* offp = off + (size_t)unit * 256 + h * 32;
    const float* rp = refp + ((size_t)b * 100 + q) * 8;
    const u16* vbase = value + (size_t)b * LEN_IN * 256 + h * 32 + c8 * 8;

    float acc[8];
#pragma unroll
    for (int k = 0; k < 8; ++k) acc[k] = 0.f;

    int start = 0;
    const int sz[4] = {128, 64, 32, 16};
#pragma unroll
    for (int l = 0; l < 4; ++l) {
        const int hh = sz[l], ww = sz[l];
        const float rx = rp[l * 2 + 0], ry = rp[l * 2 + 1];
#pragma unroll 1
        for (int pt = 0; pt < 4; ++pt) {
            float ox = offp[(l * 4 + pt) * 2 + 0];
            float oy = offp[(l * 4 + pt) * 2 + 1];
            float x = rx * ww + ox - 0.5f;
            float y = ry * hh + oy - 0.5f;
            float x0f = floorf(x), y0f = floorf(y);
            float wx = x - x0f, wy = y - y0f;
            int x0 = (int)x0f, y0 = (int)y0f;
            int x1 = x0 + 1, y1 = y0 + 1;
            float aw = w[l * 4 + pt] * inv;

            int x0c = min(max(x0, 0), ww - 1), x1c = min(max(x1, 0), ww - 1);
            int y0c = min(max(y0, 0), hh - 1), y1c = min(max(y1, 0), hh - 1);
            float w00 = aw * (1.f - wx) * (1.f - wy);
            float w10 = aw * wx * (1.f - wy);
            float w01 = aw * (1.f - wx) * wy;
            float w11 = aw * wx * wy;
            if (!(x0 >= 0 && x0 < ww)) { w00 = 0.f; w01 = 0.f; }
            if (!(x1 >= 0 && x1 < ww)) { w10 = 0.f; w11 = 0.f; }
            if (!(y0 >= 0 && y0 < hh)) { w00 = 0.f; w10 = 0.f; }
            if (!(y1 >= 0 && y1 < hh)) { w01 = 0.f; w11 = 0.f; }

            uint4 u00 = *(const uint4*)(vbase + (size_t)(start + y0c * ww + x0c) * 256);
            uint4 u10 = *(const uint4*)(vbase + (size_t)(start + y0c * ww + x1c) * 256);
            uint4 u01 = *(const uint4*)(vbase + (size_t)(start + y1c * ww + x0c) * 256);
            uint4 u11 = *(const uint4*)(vbase + (size_t)(start + y1c * ww + x1c) * 256);

#define ACC4(u, wgt) \
            acc[0] = fmaf(wgt, bf_lo(u.x), acc[0]); \
            acc[1] = fmaf(wgt, bf_hi(u.x), acc[1]); \
            acc[2] = fmaf(wgt, bf_lo(u.y), acc[2]); \
            acc[3] = fmaf(wgt, bf_hi(u.y), acc[3]); \
            acc[4] = fmaf(wgt, bf_lo(u.z), acc[4]); \
            acc[5] = fmaf(wgt, bf_hi(u.z), acc[5]); \
            acc[6] = fmaf(wgt, bf_lo(u.w), acc[6]); \
            acc[7] = fmaf(wgt, bf_hi(u.w), acc[7]);
            ACC4(u00, w00); ACC4(u10, w10); ACC4(u01, w01); ACC4(u11, w11);
#undef ACC4
        }
        start += hh * ww;
    }

    uint4 pk;
    pk.x = pack2(acc[0], acc[1]); pk.y = pack2(acc[2], acc[3]);
    pk.z = pack2(acc[4], acc[5]); pk.w = pack2(acc[6], acc[7]);
    *(uint4*)(sampled + (size_t)unit * 256 + h * 32 + c8 * 8) = pk;
}

// ---------------------------------------------------------------------------
extern "C" void kernel_launch(void* const* d_in, const int* in_sizes, int n_in,
                              void* d_out, int out_size, void* d_ws, size_t ws_size,
                              hipStream_t stream)
{
    (void)in_sizes; (void)n_in; (void)out_size; (void)ws_size;

    const float* tgt        = (const float*)d_in[0];
    const float* query_pos  = (const float*)d_in[1];
    const float* refp       = (const float*)d_in[2];
    const float* src        = (const float*)d_in[3];
    const float* w_in_intra = (const float*)d_in[4];
    const float* b_in_intra = (const float*)d_in[5];
    const float* w_out_intra= (const float*)d_in[6];
    const float* b_out_intra= (const float*)d_in[7];
    const float* g_ln_intra = (const float*)d_in[8];
    const float* b_ln_intra = (const float*)d_in[9];
    const float* w_in_inter = (const float*)d_in[10];
    const float* b_in_inter = (const float*)d_in[11];
    const float* w_out_inter= (const float*)d_in[12];
    const float* b_out_inter= (const float*)d_in[13];
    const float* g_ln_inter = (const float*)d_in[14];
    const float* b_ln_inter = (const float*)d_in[15];
    const float* off_w      = (const float*)d_in[16];
    const float* off_b      = (const float*)d_in[17];
    const float* aw_w       = (const float*)d_in[18];
    const float* aw_b       = (const float*)d_in[19];
    const float* val_w      = (const float*)d_in[20];
    const float* val_b      = (const float*)d_in[21];
    const float* co_w       = (const float*)d_in[22];
    const float* co_b       = (const float*)d_in[23];
    const float* g_ln_cross = (const float*)d_in[24];
    const float* b_ln_cross = (const float*)d_in[25];
    const float* lin1_w     = (const float*)d_in[26];
    const float* lin1_b     = (const float*)d_in[27];
    const float* lin2_w     = (const float*)d_in[28];
    const float* lin2_b     = (const float*)d_in[29];
    const float* g_ln3      = (const float*)d_in[30];
    const float* b_ln3      = (const float*)d_in[31];

    // Workspace layout (float units). Total ~37.4M floats = 150 MB.
    float* ws    = (float*)d_ws;
    float* qkv   = ws;                     // 7,680,000 fp32
    float* tmp   = ws + 7680000;           // 2,560,000 fp32
    u16*   attnb = (u16*)(ws + 10240000);  // 2,560,000 u16
    float* tgt1  = ws + 11520000;          // 2,560,000 fp32 (later: offsets)
    float* ti    = ws + 14080000;          // 2,560,000 fp32 (later: tgt2)
    u16*   tib   = (u16*)(ws + 16640000);  // 2,560,000 u16 (later: tgt2b)
    float* tA    = ws + 17920000;          // 2,560,000 fp32
    u16*   qcb   = (u16*)(ws + 20480000);  // 2,560,000 u16
    u16*   x1b   = (u16*)(ws + 21760000);  // 2,560,000 u16
    u16*   tgtb  = (u16*)(ws + 23040000);  // 2,560,000 u16
    float* awl   = ws + 24320000;          // 1,280,000 fp32
    u16*   valueb= (u16*)(ws + 25600000);  // 22,282,240 u16 (hidden overlays)
    u16*   wb    = (u16*)(ws + 36741120);  // 1,277,952 u16
    float* out   = (float*)d_out;

    // bf16 weight segment offsets in wb
    u16* wb_in_intra  = wb;
    u16* wb_out_intra = wb + 196608;
    u16* wb_in_inter  = wb + 262144;
    u16* wb_out_inter = wb + 458752;
    u16* wb_off       = wb + 524288;
    u16* wb_aw        = wb + 589824;
    u16* wb_val       = wb + 622592;
    u16* wb_co        = wb + 688128;
    u16* wb_lin1      = wb + 753664;
    u16* wb_lin2      = wb + 1015808;

    const float scale = 0.17677669529663687f;  // 1/sqrt(32)
    const int MB128 = (M10K + 127) / 128;      // 79

    // ---- one-shot conversions ----
    convert_weights_kernel<<<624, 256, 0, stream>>>(
        w_in_intra, w_out_intra, w_in_inter, w_out_inter, off_w,
        aw_w, val_w, co_w, lin1_w, lin2_w, wb);
    add_convert_kernel<<<1250, 256, 0, stream>>>(tgt, query_pos, x1b, tgtb, 320000);

    // ---- intra-instance self-attention (over 25 control points) ----
    gemm_mfma128_kernel<<<dim3(4, MB128), 256, 0, stream>>>(x1b, 256, wb_in_intra, 256,
                                                            b_in_intra, qkv, 768, M10K, 0, 0);
    gemm_mfma128_kernel<<<dim3(2, MB128), 256, 0, stream>>>(tgtb, 256, wb_in_intra + 512 * 256, 256,
                                                            b_in_intra + 512, qkv + 512, 768, M10K, 0, 0);
    intra_attn_kernel<<<400, 256, 0, stream>>>(qkv, attnb, scale);
    gemm_mfma128_kernel<<<dim3(2, MB128), 256, 0, stream>>>(attnb, 256, wb_out_intra, 256,
                                                            b_out_intra, tmp, 256, M10K, 0, 0);
    add_ln_kernel<<<M10K, 64, 0, stream>>>(tgt, tmp, g_ln_intra, b_ln_intra, tgt1, (u16*)0, 0);

    // ---- inter-instance self-attention (over 100 queries) ----
    tgt_to_ti_kernel<<<M10K, 64, 0, stream>>>(tgt1, ti, tib);
    gemm_mfma128_kernel<<<dim3(6, MB128), 256, 0, stream>>>(tib, 256, wb_in_inter, 256,
                                                            b_in_inter, qkv, 768, M10K, 0, 0);
    inter_attn_kernel<<<dim3(100, 8), 512, 0, stream>>>(qkv, attnb, scale);
    gemm_mfma128_kernel<<<dim3(2, MB128), 256, 0, stream>>>(attnb, 256, wb_out_inter, 256,
                                                            b_out_inter, tmp, 256, M10K, 0, 0);
    add_ln_kernel<<<M10K, 64, 0, stream>>>(ti, tmp, g_ln_inter, b_ln_inter, tA, (u16*)0, 1);

    // ---- deformable cross-attention ----
    add_convert_kernel<<<1250, 256, 0, stream>>>(tA, query_pos, qcb, (u16*)0, 320000);
    gemm_value_kernel<<<1360, 256, 0, stream>>>(src, wb_val, val_b, valueb, MVAL);
    gemm_mfma128_kernel<<<dim3(2, MB128), 256, 0, stream>>>(qcb, 256, wb_off, 256,
                                                            off_b, tgt1, 256, M10K, 0, 0);   // offsets
    gemm_mfma_kernel<<<dim3(2, 157), 256, 0, stream>>>(qcb, 256, wb_aw, 256,
                                                       aw_b, awl, 128, M10K);                // aw logits
    msdeform_sample_kernel<<<1250, 256, 0, stream>>>(valueb, tgt1, awl, refp, attnb);
    gemm_mfma128_kernel<<<dim3(2, MB128), 256, 0, stream>>>(attnb, 256, wb_co, 256,
                                                            co_b, tmp, 256, M10K, 0, 0);
    add_ln_kernel<<<M10K, 64, 0, stream>>>(tA, tmp, g_ln_cross, b_ln_cross, ti, tib, 0);  // tgt2

    // ---- FFN ----
    gemm_mfma128_kernel<<<dim3(8, MB128), 256, 0, stream>>>(tib, 256, wb_lin1, 256,
                                                            lin1_b, valueb, 1024, M10K, 1, 1); // hidden bf16
    gemm_mfma128_kernel<<<dim3(2, MB128), 256, 0, stream>>>(valueb, 1024, wb_lin2, 1024,
                                                            lin2_b, tmp, 256, M10K, 0, 0);
    add_ln_kernel<<<M10K, 64, 0, stream>>>(ti, tmp, g_ln3, b_ln3, out, (u16*)0, 0);
}

// Round 7
// 472.835 us; speedup vs baseline: 1.1589x; 1.1589x over previous
//
#include <hip/hip_runtime.h>
#include <math.h>

// Problem constants
#define DMODEL 256
#define HEADS  8
#define HDIM   32
#define BS     4
#define NQ     100
#define NPTS   25
#define LQ     2500      // NQ*NPTS
#define M10K   10000     // BS*LQ
#define LEN_IN 21760
#define MVAL   87040     // BS*LEN_IN

typedef float f32x4 __attribute__((ext_vector_type(4)));
typedef short s16x8 __attribute__((ext_vector_type(8)));
typedef unsigned short u16;

// fp32 -> bf16 round-to-nearest-even
static __device__ __forceinline__ short f2bf(float f) {
    unsigned u = __builtin_bit_cast(unsigned, f);
    u = (u + 0x7fffu + ((u >> 16) & 1u)) >> 16;
    return (short)u;
}
static __device__ __forceinline__ unsigned pack2(float lo, float hi) {
    return (unsigned)(u16)f2bf(lo) | ((unsigned)(u16)f2bf(hi) << 16);
}
static __device__ __forceinline__ float bf_lo(unsigned u) {
    return __builtin_bit_cast(float, u << 16);
}
static __device__ __forceinline__ float bf_hi(unsigned u) {
    return __builtin_bit_cast(float, u & 0xffff0000u);
}

#define LDSK 40   // padded bf16 row stride

// ---------------------------------------------------------------------------
// One-shot weight conversion: 10 fp32 weight matrices -> concatenated bf16.
// ---------------------------------------------------------------------------
__global__ __launch_bounds__(256) void convert_weights_kernel(
    const float* __restrict__ s0, const float* __restrict__ s1,
    const float* __restrict__ s2, const float* __restrict__ s3,
    const float* __restrict__ s4, const float* __restrict__ s5,
    const float* __restrict__ s6, const float* __restrict__ s7,
    const float* __restrict__ s8, const float* __restrict__ s9,
    u16* __restrict__ dst)
{
    int t8 = (blockIdx.x * 256 + threadIdx.x) * 8;
    if (t8 >= 1277952) return;
    const float* s; int base;
    if      (t8 <  196608) { s = s0; base = 0;       }
    else if (t8 <  262144) { s = s1; base = 196608;  }
    else if (t8 <  458752) { s = s2; base = 262144;  }
    else if (t8 <  524288) { s = s3; base = 458752;  }
    else if (t8 <  589824) { s = s4; base = 524288;  }
    else if (t8 <  622592) { s = s5; base = 589824;  }
    else if (t8 <  688128) { s = s6; base = 622592;  }
    else if (t8 <  753664) { s = s7; base = 688128;  }
    else if (t8 < 1015808) { s = s8; base = 753664;  }
    else                   { s = s9; base = 1015808; }
    const float* p = s + (t8 - base);
    float4 a = *(const float4*)p;
    float4 b = *(const float4*)(p + 4);
    s16x8 v;
    v[0]=f2bf(a.x); v[1]=f2bf(a.y); v[2]=f2bf(a.z); v[3]=f2bf(a.w);
    v[4]=f2bf(b.x); v[5]=f2bf(b.y); v[6]=f2bf(b.z); v[7]=f2bf(b.w);
    *(s16x8*)(dst + t8) = v;
}

// ---------------------------------------------------------------------------
// xb = bf16(a + b) (b optional); ab = bf16(a) (optional). 8 elems/thread.
// ---------------------------------------------------------------------------
__global__ __launch_bounds__(256) void add_convert_kernel(
    const float* __restrict__ a, const float* __restrict__ b,
    u16* __restrict__ xb, u16* __restrict__ ab, int n8)
{
    int i = blockIdx.x * 256 + threadIdx.x;
    if (i >= n8) return;
    size_t o = (size_t)i * 8;
    float4 a0 = *(const float4*)(a + o);
    float4 a1 = *(const float4*)(a + o + 4);
    if (ab) {
        s16x8 v;
        v[0]=f2bf(a0.x); v[1]=f2bf(a0.y); v[2]=f2bf(a0.z); v[3]=f2bf(a0.w);
        v[4]=f2bf(a1.x); v[5]=f2bf(a1.y); v[6]=f2bf(a1.z); v[7]=f2bf(a1.w);
        *(s16x8*)(ab + o) = v;
    }
    if (b) {
        float4 b0 = *(const float4*)(b + o);
        float4 b1 = *(const float4*)(b + o + 4);
        a0.x += b0.x; a0.y += b0.y; a0.z += b0.z; a0.w += b0.w;
        a1.x += b1.x; a1.y += b1.y; a1.z += b1.z; a1.w += b1.w;
    }
    s16x8 v;
    v[0]=f2bf(a0.x); v[1]=f2bf(a0.y); v[2]=f2bf(a0.z); v[3]=f2bf(a0.w);
    v[4]=f2bf(a1.x); v[5]=f2bf(a1.y); v[6]=f2bf(a1.z); v[7]=f2bf(a1.w);
    *(s16x8*)(xb + o) = v;
}

// ---------------------------------------------------------------------------
// 64x64-tile bf16 MFMA GEMM with register prefetch (software pipeline):
// global loads for k+1 issue before the MFMA phase of k, overlapping latency.
// C[M,N] = A[M,K] @ W[N,K]^T + bias[N]. A bf16, W bf16.
// ---------------------------------------------------------------------------
__global__ __launch_bounds__(256) void gemm_mfma_kernel(
    const u16* __restrict__ A, int lda,
    const u16* __restrict__ W, int K,
    const float* __restrict__ bias,
    void* __restrict__ Cv, int ldc,
    int M, int relu, int out_bf16)
{
    __shared__ short As[64 * LDSK];
    __shared__ short Ws[64 * LDSK];

    const int tid = threadIdx.x;
    const int m0 = blockIdx.y * 64, n0 = blockIdx.x * 64;
    const int srow = tid >> 2;
    const int skseg = (tid & 3) * 8;
    const int wave = tid >> 6;
    const int wm = wave & 1, wn = wave >> 1;
    const int lane = tid & 63;
    const int lrow = lane & 15;
    const int kq = lane >> 4;

    const int gm = m0 + srow;
    const u16* aptr = A + (size_t)gm * lda + skseg;
    const u16* wptr = W + (size_t)(n0 + srow) * K + skseg;

    f32x4 acc[2][2];
#pragma unroll
    for (int i = 0; i < 2; ++i)
#pragma unroll
        for (int j = 0; j < 2; ++j) acc[i][j] = (f32x4)(0.f);

    // prologue: load k=0
    s16x8 avr = (s16x8)0, wvr;
    if (gm < M) avr = *(const s16x8*)aptr;
    wvr = *(const s16x8*)wptr;

    for (int k0 = 0; k0 < K; k0 += 32) {
        *(s16x8*)&As[srow * LDSK + skseg] = avr;
        *(s16x8*)&Ws[srow * LDSK + skseg] = wvr;
        __syncthreads();
        if (k0 + 32 < K) {
            if (gm < M) avr = *(const s16x8*)(aptr + k0 + 32);
            wvr = *(const s16x8*)(wptr + k0 + 32);
        }

        s16x8 af[2], bfv[2];
#pragma unroll
        for (int i = 0; i < 2; ++i)
            af[i] = *(const s16x8*)&As[(wm * 32 + i * 16 + lrow) * LDSK + kq * 8];
#pragma unroll
        for (int j = 0; j < 2; ++j)
            bfv[j] = *(const s16x8*)&Ws[(wn * 32 + j * 16 + lrow) * LDSK + kq * 8];
#pragma unroll
        for (int i = 0; i < 2; ++i)
#pragma unroll
            for (int j = 0; j < 2; ++j)
                acc[i][j] = __builtin_amdgcn_mfma_f32_16x16x32_bf16(af[i], bfv[j], acc[i][j], 0, 0, 0);
        __syncthreads();
    }

#pragma unroll
    for (int i = 0; i < 2; ++i)
#pragma unroll
        for (int j = 0; j < 2; ++j) {
            int col = n0 + wn * 32 + j * 16 + lrow;
            float bv = bias[col];
#pragma unroll
            for (int reg = 0; reg < 4; ++reg) {
                int gmo = m0 + wm * 32 + i * 16 + kq * 4 + reg;
                if (gmo < M) {
                    float v = acc[i][j][reg] + bv;
                    if (relu) v = fmaxf(v, 0.f);
                    if (out_bf16)
                        ((u16*)Cv)[(size_t)gmo * ldc + col] = (u16)f2bf(v);
                    else
                        ((float*)Cv)[(size_t)gmo * ldc + col] = v;
                }
            }
        }
}

// ---------------------------------------------------------------------------
// 128x128-tile bf16 MFMA GEMM with register prefetch. Use only when grid has
// >= ~300 blocks (N >= 512 here); at N=256 the 158-block grid starves CUs.
// ---------------------------------------------------------------------------
__global__ __launch_bounds__(256) void gemm_mfma128_kernel(
    const u16* __restrict__ A, int lda,
    const u16* __restrict__ W, int K,
    const float* __restrict__ bias,
    void* __restrict__ Cv, int ldc,
    int M, int relu, int out_bf16)
{
    __shared__ short As[128 * LDSK];   // 10 KB
    __shared__ short Ws[128 * LDSK];   // 10 KB

    const int tid = threadIdx.x;
    const int m0 = blockIdx.y * 128, n0 = blockIdx.x * 128;

    const int srow = tid >> 1;            // 0..127
    const int sk = (tid & 1) * 16;        // 0 or 16

    const int wave = tid >> 6;
    const int wm = wave & 1, wn = wave >> 1;
    const int lane = tid & 63;
    const int lrow = lane & 15;
    const int kq = lane >> 4;

    const int gm = m0 + srow;
    const u16* aptr = A + (size_t)gm * lda + sk;
    const u16* wptr = W + (size_t)(n0 + srow) * K + sk;

    f32x4 acc[4][4];
#pragma unroll
    for (int i = 0; i < 4; ++i)
#pragma unroll
        for (int j = 0; j < 4; ++j) acc[i][j] = (f32x4)(0.f);

    s16x8 a0 = (s16x8)0, a1 = (s16x8)0, w0, w1;
    if (gm < M) { a0 = *(const s16x8*)aptr; a1 = *(const s16x8*)(aptr + 8); }
    w0 = *(const s16x8*)wptr; w1 = *(const s16x8*)(wptr + 8);

    for (int k0 = 0; k0 < K; k0 += 32) {
        *(s16x8*)&As[srow * LDSK + sk]     = a0;
        *(s16x8*)&As[srow * LDSK + sk + 8] = a1;
        *(s16x8*)&Ws[srow * LDSK + sk]     = w0;
        *(s16x8*)&Ws[srow * LDSK + sk + 8] = w1;
        __syncthreads();
        if (k0 + 32 < K) {
            if (gm < M) {
                a0 = *(const s16x8*)(aptr + k0 + 32);
                a1 = *(const s16x8*)(aptr + k0 + 40);
            }
            w0 = *(const s16x8*)(wptr + k0 + 32);
            w1 = *(const s16x8*)(wptr + k0 + 40);
        }

        s16x8 af[4], bfv[4];
#pragma unroll
        for (int i = 0; i < 4; ++i)
            af[i] = *(const s16x8*)&As[(wm * 64 + i * 16 + lrow) * LDSK + kq * 8];
#pragma unroll
        for (int j = 0; j < 4; ++j)
            bfv[j] = *(const s16x8*)&Ws[(wn * 64 + j * 16 + lrow) * LDSK + kq * 8];
#pragma unroll
        for (int i = 0; i < 4; ++i)
#pragma unroll
            for (int j = 0; j < 4; ++j)
                acc[i][j] = __builtin_amdgcn_mfma_f32_16x16x32_bf16(af[i], bfv[j], acc[i][j], 0, 0, 0);
        __syncthreads();
    }

#pragma unroll
    for (int i = 0; i < 4; ++i)
#pragma unroll
        for (int j = 0; j < 4; ++j) {
            int col = n0 + wn * 64 + j * 16 + lrow;
            float bv = bias[col];
#pragma unroll
            for (int reg = 0; reg < 4; ++reg) {
                int gmo = m0 + wm * 64 + i * 16 + kq * 4 + reg;
                if (gmo < M) {
                    float v = acc[i][j][reg] + bv;
                    if (relu) v = fmaxf(v, 0.f);
                    if (out_bf16)
                        ((u16*)Cv)[(size_t)gmo * ldc + col] = (u16)f2bf(v);
                    else
                        ((float*)Cv)[(size_t)gmo * ldc + col] = v;
                }
            }
        }
}

// ---------------------------------------------------------------------------
// Value GEMM: full-N tile (64 rows x 256 cols), K=N=256, register prefetch.
// A fp32 (converted during staging -- read from HBM exactly once), W bf16,
// C bf16. Wave w computes cols w*64..w*64+63 over all 64 rows.
// ---------------------------------------------------------------------------
__global__ __launch_bounds__(256) void gemm_value_kernel(
    const float* __restrict__ A,
    const u16* __restrict__ W,
    const float* __restrict__ bias,
    u16* __restrict__ C, int M)
{
    __shared__ short As[64 * LDSK];    // 5 KB
    __shared__ short Ws[256 * LDSK];   // 20.5 KB

    const int tid = threadIdx.x;
    const int m0 = blockIdx.x * 64;

    const int arow = tid >> 2;
    const int ak = (tid & 3) * 8;

    const int wave = tid >> 6;
    const int lane = tid & 63;
    const int lrow = lane & 15;
    const int kq = lane >> 4;

    const int gm = m0 + arow;
    const float* aptr = A + (size_t)gm * 256 + ak;

    f32x4 acc[4][4];
#pragma unroll
    for (int i = 0; i < 4; ++i)
#pragma unroll
        for (int j = 0; j < 4; ++j) acc[i][j] = (f32x4)(0.f);

    // prologue loads (k=0)
    float4 pa0 = make_float4(0.f,0.f,0.f,0.f), pa1 = pa0;
    if (gm < M) { pa0 = *(const float4*)aptr; pa1 = *(const float4*)(aptr + 4); }
    s16x8 pw[4];
#pragma unroll
    for (int it = 0; it < 4; ++it)
        pw[it] = *(const s16x8*)(W + (size_t)((tid >> 2) + it * 64) * 256 + ak);

    for (int k0 = 0; k0 < 256; k0 += 32) {
        s16x8 av;
        av[0]=f2bf(pa0.x); av[1]=f2bf(pa0.y); av[2]=f2bf(pa0.z); av[3]=f2bf(pa0.w);
        av[4]=f2bf(pa1.x); av[5]=f2bf(pa1.y); av[6]=f2bf(pa1.z); av[7]=f2bf(pa1.w);
        *(s16x8*)&As[arow * LDSK + ak] = av;
#pragma unroll
        for (int it = 0; it < 4; ++it)
            *(s16x8*)&Ws[((tid >> 2) + it * 64) * LDSK + ak] = pw[it];
        __syncthreads();
        if (k0 + 32 < 256) {
            if (gm < M) {
                pa0 = *(const float4*)(aptr + k0 + 32);
                pa1 = *(const float4*)(aptr + k0 + 36);
            }
#pragma unroll
            for (int it = 0; it < 4; ++it)
                pw[it] = *(const s16x8*)(W + (size_t)((tid >> 2) + it * 64) * 256 + k0 + 32 + ak);
        }

        s16x8 af[4], bfv[4];
#pragma unroll
        for (int i = 0; i < 4; ++i)
            af[i] = *(const s16x8*)&As[(i * 16 + lrow) * LDSK + kq * 8];
#pragma unroll
        for (int j = 0; j < 4; ++j)
            bfv[j] = *(const s16x8*)&Ws[(wave * 64 + j * 16 + lrow) * LDSK + kq * 8];
#pragma unroll
        for (int i = 0; i < 4; ++i)
#pragma unroll
            for (int j = 0; j < 4; ++j)
                acc[i][j] = __builtin_amdgcn_mfma_f32_16x16x32_bf16(af[i], bfv[j], acc[i][j], 0, 0, 0);
        __syncthreads();
    }

#pragma unroll
    for (int i = 0; i < 4; ++i)
#pragma unroll
        for (int j = 0; j < 4; ++j) {
            int col = wave * 64 + j * 16 + lrow;
            float bv = bias[col];
#pragma unroll
            for (int reg = 0; reg < 4; ++reg) {
                int gmo = m0 + i * 16 + kq * 4 + reg;
                if (gmo < M)
                    C[(size_t)gmo * 256 + col] = (u16)f2bf(acc[i][j][reg] + bv);
            }
        }
}

// ---------------------------------------------------------------------------
// Inter attention (S=100) via MFMA flash. One block (256 thr) per (b,h).
// S padded to 112 (7x16). Phase 1: scores = Q@K^T via 16x16x32 MFMA (D=32 =
// one k-step), scale + masked softmax fully in registers (C-layout rows:
// shuffle over the 16-lane col group + 7 ct regs), P (pre-divided by l) ->
// LDS bf16. Phase 2: PV via MFMA with V stored transposed (Vt[d][key]).
// Strides: Qs/Ks 40 u16 (16B-aligned rows), Ps/Vt 136 u16. Vt/Ps zero-filled
// (0 x junk-NaN hazard on padded keys).
// ---------------------------------------------------------------------------
__global__ __launch_bounds__(256) void inter_attn_mfma_kernel(
    const float* __restrict__ qkv, u16* __restrict__ out, float scale)
{
    __shared__ __align__(16) u16 Qs[112 * 40];
    __shared__ __align__(16) u16 Ks[112 * 40];
    __shared__ __align__(16) u16 Vt[32 * 136];
    __shared__ __align__(16) u16 Ps[112 * 136];

    const int b = blockIdx.x, h = blockIdx.y;
    const float* base = qkv + (size_t)b * 100 * 768;
    const int tid = threadIdx.x;
    const int wave = tid >> 6, lane = tid & 63;
    const int lr = lane & 15, quad = lane >> 4;

    // zero pad rows of Qs/Ks (100..111) and all of Vt/Ps
    for (int i = tid; i < 12 * 20; i += 256) {           // rows 100..111, 40 u16 = 20 u32 each
        int row = 100 + i / 20, c = (i % 20) * 2;
        *(unsigned*)&Qs[row * 40 + c] = 0;
        *(unsigned*)&Ks[row * 40 + c] = 0;
    }
    for (int i = tid; i < 2176; i += 256) ((unsigned*)Vt)[i] = 0;
    for (int i = tid; i < 7616; i += 256) ((unsigned*)Ps)[i] = 0;
    __syncthreads();

    // stage Q, K (bf16) and V transposed
    for (int idx = tid; idx < 2400; idx += 256) {
        int row = idx / 24, s = idx % 24;
        const float* p = (s < 8)  ? base + row * 768 + h * 32 + s * 4
                       : (s < 16) ? base + row * 768 + 256 + h * 32 + (s - 8) * 4
                                  : base + row * 768 + 512 + h * 32 + (s - 16) * 4;
        float4 f = *(const float4*)p;
        if (s < 8) {
            unsigned* q = (unsigned*)&Qs[row * 40 + s * 4];
            q[0] = pack2(f.x, f.y); q[1] = pack2(f.z, f.w);
        } else if (s < 16) {
            unsigned* q = (unsigned*)&Ks[row * 40 + (s - 8) * 4];
            q[0] = pack2(f.x, f.y); q[1] = pack2(f.z, f.w);
        } else {
            int d0 = (s - 16) * 4;
            Vt[(d0 + 0) * 136 + row] = (u16)f2bf(f.x);
            Vt[(d0 + 1) * 136 + row] = (u16)f2bf(f.y);
            Vt[(d0 + 2) * 136 + row] = (u16)f2bf(f.z);
            Vt[(d0 + 3) * 136 + row] = (u16)f2bf(f.w);
        }
    }
    __syncthreads();

    // ---- phase 1: scores + softmax -> Ps ----
#pragma unroll 1
    for (int rr = 0; rr < 2; ++rr) {
        int rt = wave + rr * 4;
        if (rt < 7) {
            s16x8 aq = *(const s16x8*)&Qs[(rt * 16 + lr) * 40 + quad * 8];
            f32x4 sc[7];
#pragma unroll
            for (int ct = 0; ct < 7; ++ct) {
                s16x8 bk = *(const s16x8*)&Ks[(ct * 16 + lr) * 40 + quad * 8];
                sc[ct] = __builtin_amdgcn_mfma_f32_16x16x32_bf16(aq, bk, (f32x4)(0.f), 0, 0, 0);
            }
            const bool colok[7] = {true, true, true, true, true, true, (lr < 4)};
#pragma unroll
            for (int reg = 0; reg < 4; ++reg) {
                float mx = -1e30f;
#pragma unroll
                for (int ct = 0; ct < 7; ++ct) {
                    float sv = sc[ct][reg] * scale;
                    sc[ct][reg] = sv;
                    if (colok[ct]) mx = fmaxf(mx, sv);
                }
#pragma unroll
                for (int d = 1; d < 16; d <<= 1) mx = fmaxf(mx, __shfl_xor(mx, d));
                float ssum = 0.f;
#pragma unroll
                for (int ct = 0; ct < 7; ++ct) {
                    float pv = colok[ct] ? __expf(sc[ct][reg] - mx) : 0.f;
                    sc[ct][reg] = pv;
                    ssum += pv;
                }
#pragma unroll
                for (int d = 1; d < 16; d <<= 1) ssum += __shfl_xor(ssum, d);
                float inv = 1.f / ssum;
                int prow = rt * 16 + quad * 4 + reg;
#pragma unroll
                for (int ct = 0; ct < 7; ++ct)
                    Ps[prow * 136 + ct * 16 + lr] = (u16)f2bf(sc[ct][reg] * inv);
            }
        }
    }
    __syncthreads();

    // ---- phase 2: O = P @ V ----
#pragma unroll 1
    for (int rr = 0; rr < 2; ++rr) {
        int rt = wave + rr * 4;
        if (rt < 7) {
            f32x4 o0 = (f32x4)(0.f), o1 = (f32x4)(0.f);
#pragma unroll
            for (int kk = 0; kk < 4; ++kk) {
                s16x8 ap = *(const s16x8*)&Ps[(rt * 16 + lr) * 136 + kk * 32 + quad * 8];
                s16x8 bv0 = *(const s16x8*)&Vt[lr * 136 + kk * 32 + quad * 8];
                s16x8 bv1 = *(const s16x8*)&Vt[(16 + lr) * 136 + kk * 32 + quad * 8];
                o0 = __builtin_amdgcn_mfma_f32_16x16x32_bf16(ap, bv0, o0, 0, 0, 0);
                o1 = __builtin_amdgcn_mfma_f32_16x16x32_bf16(ap, bv1, o1, 0, 0, 0);
            }
#pragma unroll
            for (int reg = 0; reg < 4; ++reg) {
                int q = rt * 16 + quad * 4 + reg;
                if (q < 100) {
                    u16* op = out + ((size_t)b * 100 + q) * 256 + h * 32;
                    op[lr]      = (u16)f2bf(o0[reg]);
                    op[16 + lr] = (u16)f2bf(o1[reg]);
                }
            }
        }
    }
}

// ---------------------------------------------------------------------------
// Intra attention (S=25). Block = 256 threads per batch-block.
// ---------------------------------------------------------------------------
__global__ __launch_bounds__(256) void intra_attn_kernel(
    const float* __restrict__ qkv, u16* __restrict__ out, float scale)
{
    __shared__ float4 KV[25][128];

    const int b = blockIdx.x;
    const int h = threadIdx.x >> 5, r = threadIdx.x & 31;
    const float* base = qkv + (size_t)b * 25 * 768;

    for (int idx = threadIdx.x; idx < 3200; idx += 256) {
        int row = idx >> 7, c = idx & 127;
        KV[row][c] = *(const float4*)(base + row * 768 + 256 + c * 4);
    }

    float q[32];
    if (r < 25) {
        const float* qp = base + r * 768 + h * 32;
#pragma unroll
        for (int c4 = 0; c4 < 8; ++c4) {
            float4 f = *(const float4*)(qp + c4 * 4);
            q[c4*4+0] = f.x; q[c4*4+1] = f.y; q[c4*4+2] = f.z; q[c4*4+3] = f.w;
        }
    }
    __syncthreads();

    if (r < 25) {
        float m = -1e30f, l = 0.f, acc[32];
#pragma unroll
        for (int c = 0; c < 32; ++c) acc[c] = 0.f;
#pragma unroll 2
        for (int j = 0; j < 25; ++j) {
            const float4* kr = &KV[j][h * 8];
            float dot = 0.f;
#pragma unroll
            for (int c4 = 0; c4 < 8; ++c4) {
                float4 kf = kr[c4];
                dot = fmaf(q[c4*4+0], kf.x, dot);
                dot = fmaf(q[c4*4+1], kf.y, dot);
                dot = fmaf(q[c4*4+2], kf.z, dot);
                dot = fmaf(q[c4*4+3], kf.w, dot);
            }
            dot *= scale;
            float mn = fmaxf(m, dot);
            float alpha = __expf(m - mn);
            float p = __expf(dot - mn);
            l = l * alpha + p;
            const float4* vr = &KV[j][64 + h * 8];
#pragma unroll
            for (int c4 = 0; c4 < 8; ++c4) {
                float4 vf = vr[c4];
                acc[c4*4+0] = acc[c4*4+0] * alpha + p * vf.x;
                acc[c4*4+1] = acc[c4*4+1] * alpha + p * vf.y;
                acc[c4*4+2] = acc[c4*4+2] * alpha + p * vf.z;
                acc[c4*4+3] = acc[c4*4+3] * alpha + p * vf.w;
            }
            m = mn;
        }
        float inv = 1.f / l;
        unsigned* op = (unsigned*)(out + ((size_t)b * 25 + r) * 256 + h * 32);
#pragma unroll
        for (int c = 0; c < 16; ++c)
            op[c] = pack2(acc[2*c] * inv, acc[2*c+1] * inv);
    }
}

// ---------------------------------------------------------------------------
// out[row] = LN(a[row] + b[row]) * g + beta; optional bf16 mirror out_bf.
// ---------------------------------------------------------------------------
__global__ __launch_bounds__(64) void add_ln_kernel(
    const float* __restrict__ a, const float* __restrict__ b,
    const float* __restrict__ g, const float* __restrict__ beta,
    float* __restrict__ out, u16* __restrict__ out_bf, int transpose_mode)
{
    const int r = blockIdx.x;
    const int lane = threadIdx.x;
    const float* ar = a + (size_t)r * 256;
    const float* br = b + (size_t)r * 256;
    float x[4];
    float s = 0.f;
#pragma unroll
    for (int i = 0; i < 4; ++i) {
        x[i] = ar[lane + 64 * i] + br[lane + 64 * i];
        s += x[i];
    }
#pragma unroll
    for (int off = 32; off >= 1; off >>= 1) s += __shfl_xor(s, off);
    float mean = s * (1.f / 256.f);
    float vs = 0.f;
#pragma unroll
    for (int i = 0; i < 4; ++i) { float d = x[i] - mean; vs += d * d; }
#pragma unroll
    for (int off = 32; off >= 1; off >>= 1) vs += __shfl_xor(vs, off);
    float rstd = rsqrtf(vs * (1.f / 256.f) + 1e-5f);

    size_t ro = r;
    if (transpose_mode) {
        int q = r % 100; int bp = r / 100; int p = bp % 25; int bb = bp / 25;
        ro = ((size_t)bb * 100 + q) * 25 + p;
    }
    float* orow = out + ro * 256;
    u16* brow = out_bf ? out_bf + ro * 256 : (u16*)0;
#pragma unroll
    for (int i = 0; i < 4; ++i) {
        int c = lane + 64 * i;
        float v = (x[i] - mean) * rstd * g[c] + beta[c];
        orow[c] = v;
        if (brow) brow[c] = (u16)f2bf(v);
    }
}

// ---------------------------------------------------------------------------
// ti[(b*25+p)*100+q][:] = tgt1[(b*100+q)*25+p][:]  (fp32 + bf16 mirror)
// ---------------------------------------------------------------------------
__global__ __launch_bounds__(64) void tgt_to_ti_kernel(
    const float* __restrict__ tgt1, float* __restrict__ ti, u16* __restrict__ tib)
{
    const int r = blockIdx.x;              // ti row
    int q = r % 100; int bp = r / 100; int p = bp % 25; int b = bp / 25;
    const float4* srcp = (const float4*)(tgt1 + (((size_t)b * 100 + q) * 25 + p) * 256);
    float4 v = srcp[threadIdx.x];
    ((float4*)(ti + (size_t)r * 256))[threadIdx.x] = v;
    uint2 pk = make_uint2(pack2(v.x, v.y), pack2(v.z, v.w));
    ((uint2*)(tib + (size_t)r * 256))[threadIdx.x] = pk;
}

// ---------------------------------------------------------------------------
// MSDeform sampling, bf16 value, 8 channels/thread, bf16 output.
// ---------------------------------------------------------------------------
__global__ __launch_bounds__(256, 4) void msdeform_sample_kernel(
    const u16* __restrict__ value,
    const float* __restrict__ off,
    const float* __restrict__ awl,
    const float* __restrict__ refp,
    u16* __restrict__ sampled)
{
    const int unit = blockIdx.x * 8 + (threadIdx.x >> 5);
    const int t = threadIdx.x & 31;
    const int h = t >> 2, c8 = t & 3;
    const int b = unit / LQ, lq = unit - b * LQ;
    const int q = lq / NPTS;

    const float* awp = awl + (size_t)unit * 128 + h * 16;
    float w[16];
    float mx = -1e30f;
#pragma unroll
    for (int k = 0; k < 16; ++k) { w[k] = awp[k]; mx = fmaxf(mx, w[k]); }
    float sum = 0.f;
#pragma unroll
    for (int k = 0; k < 16; ++k) { w[k] = __expf(w[k] - mx); sum += w[k]; }
    const float inv = 1.f / sum;

    const float* offp = off + (size_t)unit * 256 + h * 32;
    const float* rp = refp + ((size_t)b * 100 + q) * 8;
    const u16* vbase = value + (size_t)b * LEN_IN * 256 + h * 32 + c8 * 8;

    float acc[8];
#pragma unroll
    for (int k = 0; k < 8; ++k) acc[k] = 0.f;

    int start = 0;
    const int sz[4] = {128, 64, 32, 16};
#pragma unroll
    for (int l = 0; l < 4; ++l) {
        const int hh = sz[l], ww = sz[l];
        const float rx = rp[l * 2 + 0], ry = rp[l * 2 + 1];
#pragma unroll 1
        for (int pt = 0; pt < 4; ++pt) {
            float ox = offp[(l * 4 + pt) * 2 + 0];
            float oy = offp[(l * 4 + pt) * 2 + 1];
            float x = rx * ww + ox - 0.5f;
            float y = ry * hh + oy - 0.5f;
            float x0f = floorf(x), y0f = floorf(y);
            float wx = x - x0f, wy = y - y0f;
            int x0 = (int)x0f, y0 = (int)y0f;
            int x1 = x0 + 1, y1 = y0 + 1;
            float aw = w[l * 4 + pt] * inv;

            int x0c = min(max(x0, 0), ww - 1), x1c = min(max(x1, 0), ww - 1);
            int y0c = min(max(y0, 0), hh - 1), y1c = min(max(y1, 0), hh - 1);
            float w00 = aw * (1.f - wx) * (1.f - wy);
            float w10 = aw * wx * (1.f - wy);
            float w01 = aw * (1.f - wx) * wy;
            float w11 = aw * wx * wy;
            if (!(x0 >= 0 && x0 < ww)) { w00 = 0.f; w01 = 0.f; }
            if (!(x1 >= 0 && x1 < ww)) { w10 = 0.f; w11 = 0.f; }
            if (!(y0 >= 0 && y0 < hh)) { w00 = 0.f; w10 = 0.f; }
            if (!(y1 >= 0 && y1 < hh)) { w01 = 0.f; w11 = 0.f; }

            uint4 u00 = *(const uint4*)(vbase + (size_t)(start + y0c * ww + x0c) * 256);
            uint4 u10 = *(const uint4*)(vbase + (size_t)(start + y0c * ww + x1c) * 256);
            uint4 u01 = *(const uint4*)(vbase + (size_t)(start + y1c * ww + x0c) * 256);
            uint4 u11 = *(const uint4*)(vbase + (size_t)(start + y1c * ww + x1c) * 256);

#define ACC4(u, wgt) \
            acc[0] = fmaf(wgt, bf_lo(u.x), acc[0]); \
            acc[1] = fmaf(wgt, bf_hi(u.x), acc[1]); \
            acc[2] = fmaf(wgt, bf_lo(u.y), acc[2]); \
            acc[3] = fmaf(wgt, bf_hi(u.y), acc[3]); \
            acc[4] = fmaf(wgt, bf_lo(u.z), acc[4]); \
            acc[5] = fmaf(wgt, bf_hi(u.z), acc[5]); \
            acc[6] = fmaf(wgt, bf_lo(u.w), acc[6]); \
            acc[7] = fmaf(wgt, bf_hi(u.w), acc[7]);
            ACC4(u00, w00); ACC4(u10, w10); ACC4(u01, w01); ACC4(u11, w11);
#undef ACC4
        }
        start += hh * ww;
    }

    uint4 pk;
    pk.x = pack2(acc[0], acc[1]); pk.y = pack2(acc[2], acc[3]);
    pk.z = pack2(acc[4], acc[5]); pk.w = pack2(acc[6], acc[7]);
    *(uint4*)(sampled + (size_t)unit * 256 + h * 32 + c8 * 8) = pk;
}

// ---------------------------------------------------------------------------
extern "C" void kernel_launch(void* const* d_in, const int* in_sizes, int n_in,
                              void* d_out, int out_size, void* d_ws, size_t ws_size,
                              hipStream_t stream)
{
    (void)in_sizes; (void)n_in; (void)out_size; (void)ws_size;

    const float* tgt        = (const float*)d_in[0];
    const float* query_pos  = (const float*)d_in[1];
    const float* refp       = (const float*)d_in[2];
    const float* src        = (const float*)d_in[3];
    const float* w_in_intra = (const float*)d_in[4];
    const float* b_in_intra = (const float*)d_in[5];
    const float* w_out_intra= (const float*)d_in[6];
    const float* b_out_intra= (const float*)d_in[7];
    const float* g_ln_intra = (const float*)d_in[8];
    const float* b_ln_intra = (const float*)d_in[9];
    const float* w_in_inter = (const float*)d_in[10];
    const float* b_in_inter = (const float*)d_in[11];
    const float* w_out_inter= (const float*)d_in[12];
    const float* b_out_inter= (const float*)d_in[13];
    const float* g_ln_inter = (const float*)d_in[14];
    const float* b_ln_inter = (const float*)d_in[15];
    const float* off_w      = (const float*)d_in[16];
    const float* off_b      = (const float*)d_in[17];
    const float* aw_w       = (const float*)d_in[18];
    const float* aw_b       = (const float*)d_in[19];
    const float* val_w      = (const float*)d_in[20];
    const float* val_b      = (const float*)d_in[21];
    const float* co_w       = (const float*)d_in[22];
    const float* co_b       = (const float*)d_in[23];
    const float* g_ln_cross = (const float*)d_in[24];
    const float* b_ln_cross = (const float*)d_in[25];
    const float* lin1_w     = (const float*)d_in[26];
    const float* lin1_b     = (const float*)d_in[27];
    const float* lin2_w     = (const float*)d_in[28];
    const float* lin2_b     = (const float*)d_in[29];
    const float* g_ln3      = (const float*)d_in[30];
    const float* b_ln3      = (const float*)d_in[31];

    // Workspace layout (float units). Total ~37.4M floats = 150 MB.
    float* ws    = (float*)d_ws;
    float* qkv   = ws;                     // 7,680,000 fp32
    float* tmp   = ws + 7680000;           // 2,560,000 fp32
    u16*   attnb = (u16*)(ws + 10240000);  // 2,560,000 u16
    float* tgt1  = ws + 11520000;          // 2,560,000 fp32 (later: offsets)
    float* ti    = ws + 14080000;          // 2,560,000 fp32 (later: tgt2)
    u16*   tib   = (u16*)(ws + 16640000);  // 2,560,000 u16 (later: tgt2b)
    float* tA    = ws + 17920000;          // 2,560,000 fp32
    u16*   qcb   = (u16*)(ws + 20480000);  // 2,560,000 u16
    u16*   x1b   = (u16*)(ws + 21760000);  // 2,560,000 u16
    u16*   tgtb  = (u16*)(ws + 23040000);  // 2,560,000 u16
    float* awl   = ws + 24320000;          // 1,280,000 fp32
    u16*   valueb= (u16*)(ws + 25600000);  // 22,282,240 u16 (hidden overlays)
    u16*   wb    = (u16*)(ws + 36741120);  // 1,277,952 u16
    float* out   = (float*)d_out;

    // bf16 weight segment offsets in wb
    u16* wb_in_intra  = wb;
    u16* wb_out_intra = wb + 196608;
    u16* wb_in_inter  = wb + 262144;
    u16* wb_out_inter = wb + 458752;
    u16* wb_off       = wb + 524288;
    u16* wb_aw        = wb + 589824;
    u16* wb_val       = wb + 622592;
    u16* wb_co        = wb + 688128;
    u16* wb_lin1      = wb + 753664;
    u16* wb_lin2      = wb + 1015808;

    const float scale = 0.17677669529663687f;  // 1/sqrt(32)
    const int MB64  = (M10K + 63) / 64;        // 157
    const int MB128 = (M10K + 127) / 128;      // 79

    // ---- one-shot conversions ----
    convert_weights_kernel<<<624, 256, 0, stream>>>(
        w_in_intra, w_out_intra, w_in_inter, w_out_inter, off_w,
        aw_w, val_w, co_w, lin1_w, lin2_w, wb);
    add_convert_kernel<<<1250, 256, 0, stream>>>(tgt, query_pos, x1b, tgtb, 320000);

    // ---- intra-instance self-attention (over 25 control points) ----
    gemm_mfma128_kernel<<<dim3(4, MB128), 256, 0, stream>>>(x1b, 256, wb_in_intra, 256,
                                                            b_in_intra, qkv, 768, M10K, 0, 0);
    gemm_mfma_kernel<<<dim3(4, MB64), 256, 0, stream>>>(tgtb, 256, wb_in_intra + 512 * 256, 256,
                                                        b_in_intra + 512, qkv + 512, 768, M10K, 0, 0);
    intra_attn_kernel<<<400, 256, 0, stream>>>(qkv, attnb, scale);
    gemm_mfma_kernel<<<dim3(4, MB64), 256, 0, stream>>>(attnb, 256, wb_out_intra, 256,
                                                        b_out_intra, tmp, 256, M10K, 0, 0);
    add_ln_kernel<<<M10K, 64, 0, stream>>>(tgt, tmp, g_ln_intra, b_ln_intra, tgt1, (u16*)0, 0);

    // ---- inter-instance self-attention (over 100 queries) ----
    tgt_to_ti_kernel<<<M10K, 64, 0, stream>>>(tgt1, ti, tib);
    gemm_mfma128_kernel<<<dim3(6, MB128), 256, 0, stream>>>(tib, 256, wb_in_inter, 256,
                                                            b_in_inter, qkv, 768, M10K, 0, 0);
    inter_attn_mfma_kernel<<<dim3(100, 8), 256, 0, stream>>>(qkv, attnb, scale);
    gemm_mfma_kernel<<<dim3(4, MB64), 256, 0, stream>>>(attnb, 256, wb_out_inter, 256,
                                                        b_out_inter, tmp, 256, M10K, 0, 0);
    add_ln_kernel<<<M10K, 64, 0, stream>>>(ti, tmp, g_ln_inter, b_ln_inter, tA, (u16*)0, 1);

    // ---- deformable cross-attention ----
    add_convert_kernel<<<1250, 256, 0, stream>>>(tA, query_pos, qcb, (u16*)0, 320000);
    gemm_value_kernel<<<1360, 256, 0, stream>>>(src, wb_val, val_b, valueb, MVAL);
    gemm_mfma_kernel<<<dim3(4, MB64), 256, 0, stream>>>(qcb, 256, wb_off, 256,
                                                        off_b, tgt1, 256, M10K, 0, 0);     // offsets
    gemm_mfma_kernel<<<dim3(2, MB64), 256, 0, stream>>>(qcb, 256, wb_aw, 256,
                                                        aw_b, awl, 128, M10K, 0, 0);       // aw logits
    msdeform_sample_kernel<<<1250, 256, 0, stream>>>(valueb, tgt1, awl, refp, attnb);
    gemm_mfma_kernel<<<dim3(4, MB64), 256, 0, stream>>>(attnb, 256, wb_co, 256,
                                                        co_b, tmp, 256, M10K, 0, 0);
    add_ln_kernel<<<M10K, 64, 0, stream>>>(tA, tmp, g_ln_cross, b_ln_cross, ti, tib, 0);  // tgt2

    // ---- FFN ----
    gemm_mfma128_kernel<<<dim3(8, MB128), 256, 0, stream>>>(tib, 256, wb_lin1, 256,
                                                            lin1_b, valueb, 1024, M10K, 1, 1); // hidden bf16
    gemm_mfma_kernel<<<dim3(4, MB64), 256, 0, stream>>>(valueb, 1024, wb_lin2, 1024,
                                                        lin2_b, tmp, 256, M10K, 0, 0);
    add_ln_kernel<<<M10K, 64, 0, stream>>>(ti, tmp, g_ln3, b_ln3, out, (u16*)0, 0);
}

// Round 8
// 468.895 us; speedup vs baseline: 1.1686x; 1.0084x over previous
//
#include <hip/hip_runtime.h>
#include <math.h>

// Problem constants
#define DMODEL 256
#define HEADS  8
#define HDIM   32
#define BS     4
#define NQ     100
#define NPTS   25
#define LQ     2500      // NQ*NPTS
#define M10K   10000     // BS*LQ
#define LEN_IN 21760
#define MVAL   87040     // BS*LEN_IN

typedef float f32x4 __attribute__((ext_vector_type(4)));
typedef short s16x8 __attribute__((ext_vector_type(8)));
typedef unsigned short u16;

// fp32 -> bf16 round-to-nearest-even
static __device__ __forceinline__ short f2bf(float f) {
    unsigned u = __builtin_bit_cast(unsigned, f);
    u = (u + 0x7fffu + ((u >> 16) & 1u)) >> 16;
    return (short)u;
}
static __device__ __forceinline__ unsigned pack2(float lo, float hi) {
    return (unsigned)(u16)f2bf(lo) | ((unsigned)(u16)f2bf(hi) << 16);
}
static __device__ __forceinline__ float bf_lo(unsigned u) {
    return __builtin_bit_cast(float, u << 16);
}
static __device__ __forceinline__ float bf_hi(unsigned u) {
    return __builtin_bit_cast(float, u & 0xffff0000u);
}

#define LDSK   40   // padded bf16 row stride, BK=32 tiles
#define LDSK64 72   // padded bf16 row stride, BK=64 tiles

// ---------------------------------------------------------------------------
// One-shot weight conversion: 10 fp32 weight matrices -> concatenated bf16.
// ---------------------------------------------------------------------------
__global__ __launch_bounds__(256) void convert_weights_kernel(
    const float* __restrict__ s0, const float* __restrict__ s1,
    const float* __restrict__ s2, const float* __restrict__ s3,
    const float* __restrict__ s4, const float* __restrict__ s5,
    const float* __restrict__ s6, const float* __restrict__ s7,
    const float* __restrict__ s8, const float* __restrict__ s9,
    u16* __restrict__ dst)
{
    int t8 = (blockIdx.x * 256 + threadIdx.x) * 8;
    if (t8 >= 1277952) return;
    const float* s; int base;
    if      (t8 <  196608) { s = s0; base = 0;       }
    else if (t8 <  262144) { s = s1; base = 196608;  }
    else if (t8 <  458752) { s = s2; base = 262144;  }
    else if (t8 <  524288) { s = s3; base = 458752;  }
    else if (t8 <  589824) { s = s4; base = 524288;  }
    else if (t8 <  622592) { s = s5; base = 589824;  }
    else if (t8 <  688128) { s = s6; base = 622592;  }
    else if (t8 <  753664) { s = s7; base = 688128;  }
    else if (t8 < 1015808) { s = s8; base = 753664;  }
    else                   { s = s9; base = 1015808; }
    const float* p = s + (t8 - base);
    float4 a = *(const float4*)p;
    float4 b = *(const float4*)(p + 4);
    s16x8 v;
    v[0]=f2bf(a.x); v[1]=f2bf(a.y); v[2]=f2bf(a.z); v[3]=f2bf(a.w);
    v[4]=f2bf(b.x); v[5]=f2bf(b.y); v[6]=f2bf(b.z); v[7]=f2bf(b.w);
    *(s16x8*)(dst + t8) = v;
}

// ---------------------------------------------------------------------------
// xb = bf16(a + b) (b optional); ab = bf16(a) (optional). 8 elems/thread.
// ---------------------------------------------------------------------------
__global__ __launch_bounds__(256) void add_convert_kernel(
    const float* __restrict__ a, const float* __restrict__ b,
    u16* __restrict__ xb, u16* __restrict__ ab, int n8)
{
    int i = blockIdx.x * 256 + threadIdx.x;
    if (i >= n8) return;
    size_t o = (size_t)i * 8;
    float4 a0 = *(const float4*)(a + o);
    float4 a1 = *(const float4*)(a + o + 4);
    if (ab) {
        s16x8 v;
        v[0]=f2bf(a0.x); v[1]=f2bf(a0.y); v[2]=f2bf(a0.z); v[3]=f2bf(a0.w);
        v[4]=f2bf(a1.x); v[5]=f2bf(a1.y); v[6]=f2bf(a1.z); v[7]=f2bf(a1.w);
        *(s16x8*)(ab + o) = v;
    }
    if (b) {
        float4 b0 = *(const float4*)(b + o);
        float4 b1 = *(const float4*)(b + o + 4);
        a0.x += b0.x; a0.y += b0.y; a0.z += b0.z; a0.w += b0.w;
        a1.x += b1.x; a1.y += b1.y; a1.z += b1.z; a1.w += b1.w;
    }
    s16x8 v;
    v[0]=f2bf(a0.x); v[1]=f2bf(a0.y); v[2]=f2bf(a0.z); v[3]=f2bf(a0.w);
    v[4]=f2bf(a1.x); v[5]=f2bf(a1.y); v[6]=f2bf(a1.z); v[7]=f2bf(a1.w);
    *(s16x8*)(xb + o) = v;
}

// ---------------------------------------------------------------------------
// 64x64-tile bf16 MFMA GEMM, BK=64 (half the barriers of BK=32), register
// prefetch. C[M,N] = A[M,K] @ W[N,K]^T + bias[N]. K % 64 == 0.
// ---------------------------------------------------------------------------
__global__ __launch_bounds__(256) void gemm_mfma_kernel(
    const u16* __restrict__ A, int lda,
    const u16* __restrict__ W, int K,
    const float* __restrict__ bias,
    void* __restrict__ Cv, int ldc,
    int M, int relu, int out_bf16)
{
    __shared__ short As[64 * LDSK64];   // 9.2 KB
    __shared__ short Ws[64 * LDSK64];   // 9.2 KB

    const int tid = threadIdx.x;
    const int m0 = blockIdx.y * 64, n0 = blockIdx.x * 64;
    const int srow = tid >> 2;
    const int sk = (tid & 3) * 16;      // 0,16,32,48
    const int wave = tid >> 6;
    const int wm = wave & 1, wn = wave >> 1;
    const int lane = tid & 63;
    const int lrow = lane & 15;
    const int kq = lane >> 4;

    const int gm = m0 + srow;
    const u16* aptr = A + (size_t)gm * lda + sk;
    const u16* wptr = W + (size_t)(n0 + srow) * K + sk;

    f32x4 acc[2][2];
#pragma unroll
    for (int i = 0; i < 2; ++i)
#pragma unroll
        for (int j = 0; j < 2; ++j) acc[i][j] = (f32x4)(0.f);

    // prologue loads (k=0)
    s16x8 a0 = (s16x8)0, a1 = (s16x8)0, w0, w1;
    if (gm < M) { a0 = *(const s16x8*)aptr; a1 = *(const s16x8*)(aptr + 8); }
    w0 = *(const s16x8*)wptr; w1 = *(const s16x8*)(wptr + 8);

    for (int k0 = 0; k0 < K; k0 += 64) {
        *(s16x8*)&As[srow * LDSK64 + sk]     = a0;
        *(s16x8*)&As[srow * LDSK64 + sk + 8] = a1;
        *(s16x8*)&Ws[srow * LDSK64 + sk]     = w0;
        *(s16x8*)&Ws[srow * LDSK64 + sk + 8] = w1;
        __syncthreads();
        if (k0 + 64 < K) {
            if (gm < M) {
                a0 = *(const s16x8*)(aptr + k0 + 64);
                a1 = *(const s16x8*)(aptr + k0 + 72);
            }
            w0 = *(const s16x8*)(wptr + k0 + 64);
            w1 = *(const s16x8*)(wptr + k0 + 72);
        }

#pragma unroll
        for (int s = 0; s < 2; ++s) {
            s16x8 af[2], bfv[2];
#pragma unroll
            for (int i = 0; i < 2; ++i)
                af[i] = *(const s16x8*)&As[(wm * 32 + i * 16 + lrow) * LDSK64 + s * 32 + kq * 8];
#pragma unroll
            for (int j = 0; j < 2; ++j)
                bfv[j] = *(const s16x8*)&Ws[(wn * 32 + j * 16 + lrow) * LDSK64 + s * 32 + kq * 8];
#pragma unroll
            for (int i = 0; i < 2; ++i)
#pragma unroll
                for (int j = 0; j < 2; ++j)
                    acc[i][j] = __builtin_amdgcn_mfma_f32_16x16x32_bf16(af[i], bfv[j], acc[i][j], 0, 0, 0);
        }
        __syncthreads();
    }

#pragma unroll
    for (int i = 0; i < 2; ++i)
#pragma unroll
        for (int j = 0; j < 2; ++j) {
            int col = n0 + wn * 32 + j * 16 + lrow;
            float bv = bias[col];
#pragma unroll
            for (int reg = 0; reg < 4; ++reg) {
                int gmo = m0 + wm * 32 + i * 16 + kq * 4 + reg;
                if (gmo < M) {
                    float v = acc[i][j][reg] + bv;
                    if (relu) v = fmaxf(v, 0.f);
                    if (out_bf16)
                        ((u16*)Cv)[(size_t)gmo * ldc + col] = (u16)f2bf(v);
                    else
                        ((float*)Cv)[(size_t)gmo * ldc + col] = v;
                }
            }
        }
}

// ---------------------------------------------------------------------------
// 128x128-tile bf16 MFMA GEMM with register prefetch. BK=32.
// ---------------------------------------------------------------------------
__global__ __launch_bounds__(256) void gemm_mfma128_kernel(
    const u16* __restrict__ A, int lda,
    const u16* __restrict__ W, int K,
    const float* __restrict__ bias,
    void* __restrict__ Cv, int ldc,
    int M, int relu, int out_bf16)
{
    __shared__ short As[128 * LDSK];   // 10 KB
    __shared__ short Ws[128 * LDSK];   // 10 KB

    const int tid = threadIdx.x;
    const int m0 = blockIdx.y * 128, n0 = blockIdx.x * 128;

    const int srow = tid >> 1;            // 0..127
    const int sk = (tid & 1) * 16;        // 0 or 16

    const int wave = tid >> 6;
    const int wm = wave & 1, wn = wave >> 1;
    const int lane = tid & 63;
    const int lrow = lane & 15;
    const int kq = lane >> 4;

    const int gm = m0 + srow;
    const u16* aptr = A + (size_t)gm * lda + sk;
    const u16* wptr = W + (size_t)(n0 + srow) * K + sk;

    f32x4 acc[4][4];
#pragma unroll
    for (int i = 0; i < 4; ++i)
#pragma unroll
        for (int j = 0; j < 4; ++j) acc[i][j] = (f32x4)(0.f);

    s16x8 a0 = (s16x8)0, a1 = (s16x8)0, w0, w1;
    if (gm < M) { a0 = *(const s16x8*)aptr; a1 = *(const s16x8*)(aptr + 8); }
    w0 = *(const s16x8*)wptr; w1 = *(const s16x8*)(wptr + 8);

    for (int k0 = 0; k0 < K; k0 += 32) {
        *(s16x8*)&As[srow * LDSK + sk]     = a0;
        *(s16x8*)&As[srow * LDSK + sk + 8] = a1;
        *(s16x8*)&Ws[srow * LDSK + sk]     = w0;
        *(s16x8*)&Ws[srow * LDSK + sk + 8] = w1;
        __syncthreads();
        if (k0 + 32 < K) {
            if (gm < M) {
                a0 = *(const s16x8*)(aptr + k0 + 32);
                a1 = *(const s16x8*)(aptr + k0 + 40);
            }
            w0 = *(const s16x8*)(wptr + k0 + 32);
            w1 = *(const s16x8*)(wptr + k0 + 40);
        }

        s16x8 af[4], bfv[4];
#pragma unroll
        for (int i = 0; i < 4; ++i)
            af[i] = *(const s16x8*)&As[(wm * 64 + i * 16 + lrow) * LDSK + kq * 8];
#pragma unroll
        for (int j = 0; j < 4; ++j)
            bfv[j] = *(const s16x8*)&Ws[(wn * 64 + j * 16 + lrow) * LDSK + kq * 8];
#pragma unroll
        for (int i = 0; i < 4; ++i)
#pragma unroll
            for (int j = 0; j < 4; ++j)
                acc[i][j] = __builtin_amdgcn_mfma_f32_16x16x32_bf16(af[i], bfv[j], acc[i][j], 0, 0, 0);
        __syncthreads();
    }

#pragma unroll
    for (int i = 0; i < 4; ++i)
#pragma unroll
        for (int j = 0; j < 4; ++j) {
            int col = n0 + wn * 64 + j * 16 + lrow;
            float bv = bias[col];
#pragma unroll
            for (int reg = 0; reg < 4; ++reg) {
                int gmo = m0 + wm * 64 + i * 16 + kq * 4 + reg;
                if (gmo < M) {
                    float v = acc[i][j][reg] + bv;
                    if (relu) v = fmaxf(v, 0.f);
                    if (out_bf16)
                        ((u16*)Cv)[(size_t)gmo * ldc + col] = (u16)f2bf(v);
                    else
                        ((float*)Cv)[(size_t)gmo * ldc + col] = v;
                }
            }
        }
}

// ---------------------------------------------------------------------------
// Value GEMM: 128x128 tile, A fp32 (converted during staging), W bf16,
// C bf16. K = N = 256, grid (2, M/128). Register prefetch.
// ---------------------------------------------------------------------------
__global__ __launch_bounds__(256) void gemm_value128_kernel(
    const float* __restrict__ A,
    const u16* __restrict__ W,
    const float* __restrict__ bias,
    u16* __restrict__ C, int M)
{
    __shared__ short As[128 * LDSK];   // 10 KB
    __shared__ short Ws[128 * LDSK];   // 10 KB

    const int tid = threadIdx.x;
    const int m0 = blockIdx.y * 128, n0 = blockIdx.x * 128;

    const int srow = tid >> 1;            // 0..127
    const int sk = (tid & 1) * 16;        // 0 or 16

    const int wave = tid >> 6;
    const int wm = wave & 1, wn = wave >> 1;
    const int lane = tid & 63;
    const int lrow = lane & 15;
    const int kq = lane >> 4;

    const int gm = m0 + srow;
    const float* aptr = A + (size_t)gm * 256 + sk;
    const u16* wptr = W + (size_t)(n0 + srow) * 256 + sk;

    f32x4 acc[4][4];
#pragma unroll
    for (int i = 0; i < 4; ++i)
#pragma unroll
        for (int j = 0; j < 4; ++j) acc[i][j] = (f32x4)(0.f);

    float4 pa[4];
    s16x8 w0, w1;
#pragma unroll
    for (int t = 0; t < 4; ++t) pa[t] = make_float4(0.f, 0.f, 0.f, 0.f);
    if (gm < M) {
#pragma unroll
        for (int t = 0; t < 4; ++t) pa[t] = *(const float4*)(aptr + t * 4);
    }
    w0 = *(const s16x8*)wptr; w1 = *(const s16x8*)(wptr + 8);

    for (int k0 = 0; k0 < 256; k0 += 32) {
        s16x8 av0, av1;
        av0[0]=f2bf(pa[0].x); av0[1]=f2bf(pa[0].y); av0[2]=f2bf(pa[0].z); av0[3]=f2bf(pa[0].w);
        av0[4]=f2bf(pa[1].x); av0[5]=f2bf(pa[1].y); av0[6]=f2bf(pa[1].z); av0[7]=f2bf(pa[1].w);
        av1[0]=f2bf(pa[2].x); av1[1]=f2bf(pa[2].y); av1[2]=f2bf(pa[2].z); av1[3]=f2bf(pa[2].w);
        av1[4]=f2bf(pa[3].x); av1[5]=f2bf(pa[3].y); av1[6]=f2bf(pa[3].z); av1[7]=f2bf(pa[3].w);
        *(s16x8*)&As[srow * LDSK + sk]     = av0;
        *(s16x8*)&As[srow * LDSK + sk + 8] = av1;
        *(s16x8*)&Ws[srow * LDSK + sk]     = w0;
        *(s16x8*)&Ws[srow * LDSK + sk + 8] = w1;
        __syncthreads();
        if (k0 + 32 < 256) {
            if (gm < M) {
#pragma unroll
                for (int t = 0; t < 4; ++t)
                    pa[t] = *(const float4*)(aptr + k0 + 32 + t * 4);
            }
            w0 = *(const s16x8*)(wptr + k0 + 32);
            w1 = *(const s16x8*)(wptr + k0 + 40);
        }

        s16x8 af[4], bfv[4];
#pragma unroll
        for (int i = 0; i < 4; ++i)
            af[i] = *(const s16x8*)&As[(wm * 64 + i * 16 + lrow) * LDSK + kq * 8];
#pragma unroll
        for (int j = 0; j < 4; ++j)
            bfv[j] = *(const s16x8*)&Ws[(wn * 64 + j * 16 + lrow) * LDSK + kq * 8];
#pragma unroll
        for (int i = 0; i < 4; ++i)
#pragma unroll
            for (int j = 0; j < 4; ++j)
                acc[i][j] = __builtin_amdgcn_mfma_f32_16x16x32_bf16(af[i], bfv[j], acc[i][j], 0, 0, 0);
        __syncthreads();
    }

#pragma unroll
    for (int i = 0; i < 4; ++i)
#pragma unroll
        for (int j = 0; j < 4; ++j) {
            int col = n0 + wn * 64 + j * 16 + lrow;
            float bv = bias[col];
#pragma unroll
            for (int reg = 0; reg < 4; ++reg) {
                int gmo = m0 + wm * 64 + i * 16 + kq * 4 + reg;
                if (gmo < M)
                    C[(size_t)gmo * 256 + col] = (u16)f2bf(acc[i][j][reg] + bv);
            }
        }
}

// ---------------------------------------------------------------------------
// Inter attention (S=100) via MFMA flash. One block (256 thr) per (b,h).
// ---------------------------------------------------------------------------
__global__ __launch_bounds__(256) void inter_attn_mfma_kernel(
    const float* __restrict__ qkv, u16* __restrict__ out, float scale)
{
    __shared__ __align__(16) u16 Qs[112 * 40];
    __shared__ __align__(16) u16 Ks[112 * 40];
    __shared__ __align__(16) u16 Vt[32 * 136];
    __shared__ __align__(16) u16 Ps[112 * 136];

    const int b = blockIdx.x, h = blockIdx.y;
    const float* base = qkv + (size_t)b * 100 * 768;
    const int tid = threadIdx.x;
    const int wave = tid >> 6, lane = tid & 63;
    const int lr = lane & 15, quad = lane >> 4;

    for (int i = tid; i < 12 * 20; i += 256) {
        int row = 100 + i / 20, c = (i % 20) * 2;
        *(unsigned*)&Qs[row * 40 + c] = 0;
        *(unsigned*)&Ks[row * 40 + c] = 0;
    }
    for (int i = tid; i < 2176; i += 256) ((unsigned*)Vt)[i] = 0;
    for (int i = tid; i < 7616; i += 256) ((unsigned*)Ps)[i] = 0;
    __syncthreads();

    for (int idx = tid; idx < 2400; idx += 256) {
        int row = idx / 24, s = idx % 24;
        const float* p = (s < 8)  ? base + row * 768 + h * 32 + s * 4
                       : (s < 16) ? base + row * 768 + 256 + h * 32 + (s - 8) * 4
                                  : base + row * 768 + 512 + h * 32 + (s - 16) * 4;
        float4 f = *(const float4*)p;
        if (s < 8) {
            unsigned* q = (unsigned*)&Qs[row * 40 + s * 4];
            q[0] = pack2(f.x, f.y); q[1] = pack2(f.z, f.w);
        } else if (s < 16) {
            unsigned* q = (unsigned*)&Ks[row * 40 + (s - 8) * 4];
            q[0] = pack2(f.x, f.y); q[1] = pack2(f.z, f.w);
        } else {
            int d0 = (s - 16) * 4;
            Vt[(d0 + 0) * 136 + row] = (u16)f2bf(f.x);
            Vt[(d0 + 1) * 136 + row] = (u16)f2bf(f.y);
            Vt[(d0 + 2) * 136 + row] = (u16)f2bf(f.z);
            Vt[(d0 + 3) * 136 + row] = (u16)f2bf(f.w);
        }
    }
    __syncthreads();

#pragma unroll 1
    for (int rr = 0; rr < 2; ++rr) {
        int rt = wave + rr * 4;
        if (rt < 7) {
            s16x8 aq = *(const s16x8*)&Qs[(rt * 16 + lr) * 40 + quad * 8];
            f32x4 sc[7];
#pragma unroll
            for (int ct = 0; ct < 7; ++ct) {
                s16x8 bk = *(const s16x8*)&Ks[(ct * 16 + lr) * 40 + quad * 8];
                sc[ct] = __builtin_amdgcn_mfma_f32_16x16x32_bf16(aq, bk, (f32x4)(0.f), 0, 0, 0);
            }
            const bool colok[7] = {true, true, true, true, true, true, (lr < 4)};
#pragma unroll
            for (int reg = 0; reg < 4; ++reg) {
                float mx = -1e30f;
#pragma unroll
                for (int ct = 0; ct < 7; ++ct) {
                    float sv = sc[ct][reg] * scale;
                    sc[ct][reg] = sv;
                    if (colok[ct]) mx = fmaxf(mx, sv);
                }
#pragma unroll
                for (int d = 1; d < 16; d <<= 1) mx = fmaxf(mx, __shfl_xor(mx, d));
                float ssum = 0.f;
#pragma unroll
                for (int ct = 0; ct < 7; ++ct) {
                    float pv = colok[ct] ? __expf(sc[ct][reg] - mx) : 0.f;
                    sc[ct][reg] = pv;
                    ssum += pv;
                }
#pragma unroll
                for (int d = 1; d < 16; d <<= 1) ssum += __shfl_xor(ssum, d);
                float inv = 1.f / ssum;
                int prow = rt * 16 + quad * 4 + reg;
#pragma unroll
                for (int ct = 0; ct < 7; ++ct)
                    Ps[prow * 136 + ct * 16 + lr] = (u16)f2bf(sc[ct][reg] * inv);
            }
        }
    }
    __syncthreads();

#pragma unroll 1
    for (int rr = 0; rr < 2; ++rr) {
        int rt = wave + rr * 4;
        if (rt < 7) {
            f32x4 o0 = (f32x4)(0.f), o1 = (f32x4)(0.f);
#pragma unroll
            for (int kk = 0; kk < 4; ++kk) {
                s16x8 ap = *(const s16x8*)&Ps[(rt * 16 + lr) * 136 + kk * 32 + quad * 8];
                s16x8 bv0 = *(const s16x8*)&Vt[lr * 136 + kk * 32 + quad * 8];
                s16x8 bv1 = *(const s16x8*)&Vt[(16 + lr) * 136 + kk * 32 + quad * 8];
                o0 = __builtin_amdgcn_mfma_f32_16x16x32_bf16(ap, bv0, o0, 0, 0, 0);
                o1 = __builtin_amdgcn_mfma_f32_16x16x32_bf16(ap, bv1, o1, 0, 0, 0);
            }
#pragma unroll
            for (int reg = 0; reg < 4; ++reg) {
                int q = rt * 16 + quad * 4 + reg;
                if (q < 100) {
                    u16* op = out + ((size_t)b * 100 + q) * 256 + h * 32;
                    op[lr]      = (u16)f2bf(o0[reg]);
                    op[16 + lr] = (u16)f2bf(o1[reg]);
                }
            }
        }
    }
}

// ---------------------------------------------------------------------------
// Intra attention (S=25). Block = 256 threads per batch-block.
// ---------------------------------------------------------------------------
__global__ __launch_bounds__(256) void intra_attn_kernel(
    const float* __restrict__ qkv, u16* __restrict__ out, float scale)
{
    __shared__ float4 KV[25][128];

    const int b = blockIdx.x;
    const int h = threadIdx.x >> 5, r = threadIdx.x & 31;
    const float* base = qkv + (size_t)b * 25 * 768;

    for (int idx = threadIdx.x; idx < 3200; idx += 256) {
        int row = idx >> 7, c = idx & 127;
        KV[row][c] = *(const float4*)(base + row * 768 + 256 + c * 4);
    }

    float q[32];
    if (r < 25) {
        const float* qp = base + r * 768 + h * 32;
#pragma unroll
        for (int c4 = 0; c4 < 8; ++c4) {
            float4 f = *(const float4*)(qp + c4 * 4);
            q[c4*4+0] = f.x; q[c4*4+1] = f.y; q[c4*4+2] = f.z; q[c4*4+3] = f.w;
        }
    }
    __syncthreads();

    if (r < 25) {
        float m = -1e30f, l = 0.f, acc[32];
#pragma unroll
        for (int c = 0; c < 32; ++c) acc[c] = 0.f;
#pragma unroll 2
        for (int j = 0; j < 25; ++j) {
            const float4* kr = &KV[j][h * 8];
            float dot = 0.f;
#pragma unroll
            for (int c4 = 0; c4 < 8; ++c4) {
                float4 kf = kr[c4];
                dot = fmaf(q[c4*4+0], kf.x, dot);
                dot = fmaf(q[c4*4+1], kf.y, dot);
                dot = fmaf(q[c4*4+2], kf.z, dot);
                dot = fmaf(q[c4*4+3], kf.w, dot);
            }
            dot *= scale;
            float mn = fmaxf(m, dot);
            float alpha = __expf(m - mn);
            float p = __expf(dot - mn);
            l = l * alpha + p;
            const float4* vr = &KV[j][64 + h * 8];
#pragma unroll
            for (int c4 = 0; c4 < 8; ++c4) {
                float4 vf = vr[c4];
                acc[c4*4+0] = acc[c4*4+0] * alpha + p * vf.x;
                acc[c4*4+1] = acc[c4*4+1] * alpha + p * vf.y;
                acc[c4*4+2] = acc[c4*4+2] * alpha + p * vf.z;
                acc[c4*4+3] = acc[c4*4+3] * alpha + p * vf.w;
            }
            m = mn;
        }
        float inv = 1.f / l;
        unsigned* op = (unsigned*)(out + ((size_t)b * 25 + r) * 256 + h * 32);
#pragma unroll
        for (int c = 0; c < 16; ++c)
            op[c] = pack2(acc[2*c] * inv, acc[2*c+1] * inv);
    }
}

// ---------------------------------------------------------------------------
// out[row] = LN(a[row] + b[row]) * g + beta; optional bf16 mirror out_bf.
// ---------------------------------------------------------------------------
__global__ __launch_bounds__(64) void add_ln_kernel(
    const float* __restrict__ a, const float* __restrict__ b,
    const float* __restrict__ g, const float* __restrict__ beta,
    float* __restrict__ out, u16* __restrict__ out_bf, int transpose_mode)
{
    const int r = blockIdx.x;
    const int lane = threadIdx.x;
    const float* ar = a + (size_t)r * 256;
    const float* br = b + (size_t)r * 256;
    float x[4];
    float s = 0.f;
#pragma unroll
    for (int i = 0; i < 4; ++i) {
        x[i] = ar[lane + 64 * i] + br[lane + 64 * i];
        s += x[i];
    }
#pragma unroll
    for (int off = 32; off >= 1; off >>= 1) s += __shfl_xor(s, off);
    float mean = s * (1.f / 256.f);
    float vs = 0.f;
#pragma unroll
    for (int i = 0; i < 4; ++i) { float d = x[i] - mean; vs += d * d; }
#pragma unroll
    for (int off = 32; off >= 1; off >>= 1) vs += __shfl_xor(vs, off);
    float rstd = rsqrtf(vs * (1.f / 256.f) + 1e-5f);

    size_t ro = r;
    if (transpose_mode) {
        int q = r % 100; int bp = r / 100; int p = bp % 25; int bb = bp / 25;
        ro = ((size_t)bb * 100 + q) * 25 + p;
    }
    float* orow = out + ro * 256;
    u16* brow = out_bf ? out_bf + ro * 256 : (u16*)0;
#pragma unroll
    for (int i = 0; i < 4; ++i) {
        int c = lane + 64 * i;
        float v = (x[i] - mean) * rstd * g[c] + beta[c];
        orow[c] = v;
        if (brow) brow[c] = (u16)f2bf(v);
    }
}

// ---------------------------------------------------------------------------
// ti[(b*25+p)*100+q][:] = tgt1[(b*100+q)*25+p][:]  (fp32 + bf16 mirror)
// ---------------------------------------------------------------------------
__global__ __launch_bounds__(64) void tgt_to_ti_kernel(
    const float* __restrict__ tgt1, float* __restrict__ ti, u16* __restrict__ tib)
{
    const int r = blockIdx.x;              // ti row
    int q = r % 100; int bp = r / 100; int p = bp % 25; int b = bp / 25;
    const float4* srcp = (const float4*)(tgt1 + (((size_t)b * 100 + q) * 25 + p) * 256);
    float4 v = srcp[threadIdx.x];
    ((float4*)(ti + (size_t)r * 256))[threadIdx.x] = v;
    uint2 pk = make_uint2(pack2(v.x, v.y), pack2(v.z, v.w));
    ((uint2*)(tib + (size_t)r * 256))[threadIdx.x] = pk;
}

// ---------------------------------------------------------------------------
// MSDeform sampling, bf16 value, 8 channels/thread, bf16 output.
// ---------------------------------------------------------------------------
__global__ __launch_bounds__(256, 4) void msdeform_sample_kernel(
    const u16* __restrict__ value,
    const float* __restrict__ off,
    const float* __restrict__ awl,
    const float* __restrict__ refp,
    u16* __restrict__ sampled)
{
    const int unit = blockIdx.x * 8 + (threadIdx.x >> 5);
    const int t = threadIdx.x & 31;
    const int h = t >> 2, c8 = t & 3;
    const int b = unit / LQ, lq = unit - b * LQ;
    const int q = lq / NPTS;

    const float* awp = awl + (size_t)unit * 128 + h * 16;
    float w[16];
    float mx = -1e30f;
#pragma unroll
    for (int k = 0; k < 16; ++k) { w[k] = awp[k]; mx = fmaxf(mx, w[k]); }
    float sum = 0.f;
#pragma unroll
    for (int k = 0; k < 16; ++k) { w[k] = __expf(w[k] - mx); sum += w[k]; }
    const float inv = 1.f / sum;

    const float* offp = off + (size_t)unit * 256 + h * 32;
    const float* rp = refp + ((size_t)b * 100 + q) * 8;
    const u16* vbase = value + (size_t)b * LEN_IN * 256 + h * 32 + c8 * 8;

    float acc[8];
#pragma unroll
    for (int k = 0; k < 8; ++k) acc[k] = 0.f;

    int start = 0;
    const int sz[4] = {128, 64, 32, 16};
#pragma unroll
    for (int l = 0; l < 4; ++l) {
        const int hh = sz[l], ww = sz[l];
        const float rx = rp[l * 2 + 0], ry = rp[l * 2 + 1];
#pragma unroll 1
        for (int pt = 0; pt < 4; ++pt) {
            float ox = offp[(l * 4 + pt) * 2 + 0];
            float oy = offp[(l * 4 + pt) * 2 + 1];
            float x = rx * ww + ox - 0.5f;
            float y = ry * hh + oy - 0.5f;
            float x0f = floorf(x), y0f = floorf(y);
            float wx = x - x0f, wy = y - y0f;
            int x0 = (int)x0f, y0 = (int)y0f;
            int x1 = x0 + 1, y1 = y0 + 1;
            float aw = w[l * 4 + pt] * inv;

            int x0c = min(max(x0, 0), ww - 1), x1c = min(max(x1, 0), ww - 1);
            int y0c = min(max(y0, 0), hh - 1), y1c = min(max(y1, 0), hh - 1);
            float w00 = aw * (1.f - wx) * (1.f - wy);
            float w10 = aw * wx * (1.f - wy);
            float w01 = aw * (1.f - wx) * wy;
            float w11 = aw * wx * wy;
            if (!(x0 >= 0 && x0 < ww)) { w00 = 0.f; w01 = 0.f; }
            if (!(x1 >= 0 && x1 < ww)) { w10 = 0.f; w11 = 0.f; }
            if (!(y0 >= 0 && y0 < hh)) { w00 = 0.f; w10 = 0.f; }
            if (!(y1 >= 0 && y1 < hh)) { w01 = 0.f; w11 = 0.f; }

            uint4 u00 = *(const uint4*)(vbase + (size_t)(start + y0c * ww + x0c) * 256);
            uint4 u10 = *(const uint4*)(vbase + (size_t)(start + y0c * ww + x1c) * 256);
            uint4 u01 = *(const uint4*)(vbase + (size_t)(start + y1c * ww + x0c) * 256);
            uint4 u11 = *(const uint4*)(vbase + (size_t)(start + y1c * ww + x1c) * 256);

#define ACC4(u, wgt) \
            acc[0] = fmaf(wgt, bf_lo(u.x), acc[0]); \
            acc[1] = fmaf(wgt, bf_hi(u.x), acc[1]); \
            acc[2] = fmaf(wgt, bf_lo(u.y), acc[2]); \
            acc[3] = fmaf(wgt, bf_hi(u.y), acc[3]); \
            acc[4] = fmaf(wgt, bf_lo(u.z), acc[4]); \
            acc[5] = fmaf(wgt, bf_hi(u.z), acc[5]); \
            acc[6] = fmaf(wgt, bf_lo(u.w), acc[6]); \
            acc[7] = fmaf(wgt, bf_hi(u.w), acc[7]);
            ACC4(u00, w00); ACC4(u10, w10); ACC4(u01, w01); ACC4(u11, w11);
#undef ACC4
        }
        start += hh * ww;
    }

    uint4 pk;
    pk.x = pack2(acc[0], acc[1]); pk.y = pack2(acc[2], acc[3]);
    pk.z = pack2(acc[4], acc[5]); pk.w = pack2(acc[6], acc[7]);
    *(uint4*)(sampled + (size_t)unit * 256 + h * 32 + c8 * 8) = pk;
}

// ---------------------------------------------------------------------------
extern "C" void kernel_launch(void* const* d_in, const int* in_sizes, int n_in,
                              void* d_out, int out_size, void* d_ws, size_t ws_size,
                              hipStream_t stream)
{
    (void)in_sizes; (void)n_in; (void)out_size; (void)ws_size;

    const float* tgt        = (const float*)d_in[0];
    const float* query_pos  = (const float*)d_in[1];
    const float* refp       = (const float*)d_in[2];
    const float* src        = (const float*)d_in[3];
    const float* w_in_intra = (const float*)d_in[4];
    const float* b_in_intra = (const float*)d_in[5];
    const float* w_out_intra= (const float*)d_in[6];
    const float* b_out_intra= (const float*)d_in[7];
    const float* g_ln_intra = (const float*)d_in[8];
    const float* b_ln_intra = (const float*)d_in[9];
    const float* w_in_inter = (const float*)d_in[10];
    const float* b_in_inter = (const float*)d_in[11];
    const float* w_out_inter= (const float*)d_in[12];
    const float* b_out_inter= (const float*)d_in[13];
    const float* g_ln_inter = (const float*)d_in[14];
    const float* b_ln_inter = (const float*)d_in[15];
    const float* off_w      = (const float*)d_in[16];
    const float* off_b      = (const float*)d_in[17];
    const float* aw_w       = (const float*)d_in[18];
    const float* aw_b       = (const float*)d_in[19];
    const float* val_w      = (const float*)d_in[20];
    const float* val_b      = (const float*)d_in[21];
    const float* co_w       = (const float*)d_in[22];
    const float* co_b       = (const float*)d_in[23];
    const float* g_ln_cross = (const float*)d_in[24];
    const float* b_ln_cross = (const float*)d_in[25];
    const float* lin1_w     = (const float*)d_in[26];
    const float* lin1_b     = (const float*)d_in[27];
    const float* lin2_w     = (const float*)d_in[28];
    const float* lin2_b     = (const float*)d_in[29];
    const float* g_ln3      = (const float*)d_in[30];
    const float* b_ln3      = (const float*)d_in[31];

    // Workspace layout (float units). Total ~37.4M floats = 150 MB.
    float* ws    = (float*)d_ws;
    float* qkv   = ws;                     // 7,680,000 fp32
    float* tmp   = ws + 7680000;           // 2,560,000 fp32
    u16*   attnb = (u16*)(ws + 10240000);  // 2,560,000 u16
    float* tgt1  = ws + 11520000;          // 2,560,000 fp32 (later: offsets)
    float* ti    = ws + 14080000;          // 2,560,000 fp32 (later: tgt2)
    u16*   tib   = (u16*)(ws + 16640000);  // 2,560,000 u16 (later: tgt2b)
    float* tA    = ws + 17920000;          // 2,560,000 fp32
    u16*   qcb   = (u16*)(ws + 20480000);  // 2,560,000 u16
    u16*   x1b   = (u16*)(ws + 21760000);  // 2,560,000 u16
    u16*   tgtb  = (u16*)(ws + 23040000);  // 2,560,000 u16
    float* awl   = ws + 24320000;          // 1,280,000 fp32
    u16*   valueb= (u16*)(ws + 25600000);  // 22,282,240 u16 (hidden overlays)
    u16*   wb    = (u16*)(ws + 36741120);  // 1,277,952 u16
    float* out   = (float*)d_out;

    // bf16 weight segment offsets in wb
    u16* wb_in_intra  = wb;
    u16* wb_out_intra = wb + 196608;
    u16* wb_in_inter  = wb + 262144;
    u16* wb_out_inter = wb + 458752;
    u16* wb_off       = wb + 524288;
    u16* wb_aw        = wb + 589824;
    u16* wb_val       = wb + 622592;
    u16* wb_co        = wb + 688128;
    u16* wb_lin1      = wb + 753664;
    u16* wb_lin2      = wb + 1015808;

    const float scale = 0.17677669529663687f;  // 1/sqrt(32)
    const int MB64  = (M10K + 63) / 64;        // 157
    const int MB128 = (M10K + 127) / 128;      // 79

    // ---- one-shot conversions ----
    convert_weights_kernel<<<624, 256, 0, stream>>>(
        w_in_intra, w_out_intra, w_in_inter, w_out_inter, off_w,
        aw_w, val_w, co_w, lin1_w, lin2_w, wb);
    add_convert_kernel<<<1250, 256, 0, stream>>>(tgt, query_pos, x1b, tgtb, 320000);

    // ---- intra-instance self-attention (over 25 control points) ----
    gemm_mfma128_kernel<<<dim3(4, MB128), 256, 0, stream>>>(x1b, 256, wb_in_intra, 256,
                                                            b_in_intra, qkv, 768, M10K, 0, 0);
    gemm_mfma_kernel<<<dim3(4, MB64), 256, 0, stream>>>(tgtb, 256, wb_in_intra + 512 * 256, 256,
                                                        b_in_intra + 512, qkv + 512, 768, M10K, 0, 0);
    intra_attn_kernel<<<400, 256, 0, stream>>>(qkv, attnb, scale);
    gemm_mfma_kernel<<<dim3(4, MB64), 256, 0, stream>>>(attnb, 256, wb_out_intra, 256,
                                                        b_out_intra, tmp, 256, M10K, 0, 0);
    add_ln_kernel<<<M10K, 64, 0, stream>>>(tgt, tmp, g_ln_intra, b_ln_intra, tgt1, (u16*)0, 0);

    // ---- inter-instance self-attention (over 100 queries) ----
    tgt_to_ti_kernel<<<M10K, 64, 0, stream>>>(tgt1, ti, tib);
    gemm_mfma128_kernel<<<dim3(6, MB128), 256, 0, stream>>>(tib, 256, wb_in_inter, 256,
                                                            b_in_inter, qkv, 768, M10K, 0, 0);
    inter_attn_mfma_kernel<<<dim3(100, 8), 256, 0, stream>>>(qkv, attnb, scale);
    gemm_mfma_kernel<<<dim3(4, MB64), 256, 0, stream>>>(attnb, 256, wb_out_inter, 256,
                                                        b_out_inter, tmp, 256, M10K, 0, 0);
    add_ln_kernel<<<M10K, 64, 0, stream>>>(ti, tmp, g_ln_inter, b_ln_inter, tA, (u16*)0, 1);

    // ---- deformable cross-attention ----
    add_convert_kernel<<<1250, 256, 0, stream>>>(tA, query_pos, qcb, (u16*)0, 320000);
    gemm_value128_kernel<<<dim3(2, 680), 256, 0, stream>>>(src, wb_val, val_b, valueb, MVAL);
    gemm_mfma_kernel<<<dim3(4, MB64), 256, 0, stream>>>(qcb, 256, wb_off, 256,
                                                        off_b, tgt1, 256, M10K, 0, 0);     // offsets
    gemm_mfma_kernel<<<dim3(2, MB64), 256, 0, stream>>>(qcb, 256, wb_aw, 256,
                                                        aw_b, awl, 128, M10K, 0, 0);       // aw logits
    msdeform_sample_kernel<<<1250, 256, 0, stream>>>(valueb, tgt1, awl, refp, attnb);
    gemm_mfma_kernel<<<dim3(4, MB64), 256, 0, stream>>>(attnb, 256, wb_co, 256,
                                                        co_b, tmp, 256, M10K, 0, 0);
    add_ln_kernel<<<M10K, 64, 0, stream>>>(tA, tmp, g_ln_cross, b_ln_cross, ti, tib, 0);  // tgt2

    // ---- FFN ----
    gemm_mfma128_kernel<<<dim3(8, MB128), 256, 0, stream>>>(tib, 256, wb_lin1, 256,
                                                            lin1_b, valueb, 1024, M10K, 1, 1); // hidden bf16
    gemm_mfma_kernel<<<dim3(4, MB64), 256, 0, stream>>>(valueb, 1024, wb_lin2, 1024,
                                                        lin2_b, tmp, 256, M10K, 0, 0);
    add_ln_kernel<<<M10K, 64, 0, stream>>>(ti, tmp, g_ln3, b_ln3, out, (u16*)0, 0);
}